// Round 5
// baseline (1737.652 us; speedup 1.0000x reference)
//
#include <hip/hip_runtime.h>

#define TPB 256
#define TPF 1024
constexpr int LS = 264600;          // 6.0 s * 44100 Hz
constexpr int N1 = 525;             // LS = N1 * N2
constexpr int N2 = 504;
constexpr int ROWS = 32;            // S*C = 16*2
constexpr int M_FFT = 16384;        // Bluestein conv length >= 2*NL-1 (NL<=8192)
constexpr float TWO_PI_F = 6.28318530717958647692f;
constexpr float PI_F     = 3.14159265358979323846f;

__device__ __forceinline__ float2 cmul(float2 a, float2 b) {
    return make_float2(a.x * b.x - a.y * b.y, a.x * b.y + a.y * b.x);
}
// XOR-swizzled LDS index for the 128x128 array: row-wise, column-wise and
// linear wave accesses all conflict-free (16 distinct bank-pairs / 16 lanes).
__device__ __forceinline__ int sidx(int hi, int lo) {
    return (hi << 7) + (lo ^ (hi & 15));
}

// ---------------------------------------------------------------------------
// Register FFT networks on NAMED scalars (no arrays -> guaranteed VGPRs).
// DIF, natural in, bit-reversed out. Twiddles are compile-time immediates.
// ---------------------------------------------------------------------------
#define BFLY(u, w, C, S) do {                       \
    float dx_ = (u).x - (w).x, dy_ = (u).y - (w).y; \
    (u).x += (w).x; (u).y += (w).y;                 \
    (w).x = dx_ * (C) - dy_ * (S);                  \
    (w).y = dx_ * (S) + dy_ * (C);                  \
} while (0)

template<bool INV>
__device__ __forceinline__ void fft16s(float2 &a0, float2 &a1, float2 &a2, float2 &a3,
                                       float2 &a4, float2 &a5, float2 &a6, float2 &a7,
                                       float2 &a8, float2 &a9, float2 &a10, float2 &a11,
                                       float2 &a12, float2 &a13, float2 &a14, float2 &a15) {
    constexpr float c1 = 0.92387953251128674f;
    constexpr float s1 = 0.38268343236508977f;
    constexpr float r2 = 0.70710678118654752f;
    const float sg = INV ? 1.f : -1.f;
    // span 8 (ti = j)
    BFLY(a0, a8,  1.f, 0.f);
    BFLY(a1, a9,  c1,  sg * s1);
    BFLY(a2, a10, r2,  sg * r2);
    BFLY(a3, a11, s1,  sg * c1);
    BFLY(a4, a12, 0.f, sg * 1.f);
    BFLY(a5, a13, -s1, sg * c1);
    BFLY(a6, a14, -r2, sg * r2);
    BFLY(a7, a15, -c1, sg * s1);
    // span 4 (ti = 2j)
    BFLY(a0, a4,  1.f, 0.f);
    BFLY(a1, a5,  r2,  sg * r2);
    BFLY(a2, a6,  0.f, sg * 1.f);
    BFLY(a3, a7,  -r2, sg * r2);
    BFLY(a8, a12, 1.f, 0.f);
    BFLY(a9, a13, r2,  sg * r2);
    BFLY(a10, a14, 0.f, sg * 1.f);
    BFLY(a11, a15, -r2, sg * r2);
    // span 2 (ti = 4j)
    BFLY(a0, a2,  1.f, 0.f);
    BFLY(a1, a3,  0.f, sg * 1.f);
    BFLY(a4, a6,  1.f, 0.f);
    BFLY(a5, a7,  0.f, sg * 1.f);
    BFLY(a8, a10, 1.f, 0.f);
    BFLY(a9, a11, 0.f, sg * 1.f);
    BFLY(a12, a14, 1.f, 0.f);
    BFLY(a13, a15, 0.f, sg * 1.f);
    // span 1
    BFLY(a0, a1,  1.f, 0.f);
    BFLY(a2, a3,  1.f, 0.f);
    BFLY(a4, a5,  1.f, 0.f);
    BFLY(a6, a7,  1.f, 0.f);
    BFLY(a8, a9,  1.f, 0.f);
    BFLY(a10, a11, 1.f, 0.f);
    BFLY(a12, a13, 1.f, 0.f);
    BFLY(a14, a15, 1.f, 0.f);
}

template<bool INV>
__device__ __forceinline__ void fft8s(float2 &b0, float2 &b1, float2 &b2, float2 &b3,
                                      float2 &b4, float2 &b5, float2 &b6, float2 &b7) {
    constexpr float r2 = 0.70710678118654752f;
    const float sg = INV ? 1.f : -1.f;
    BFLY(b0, b4, 1.f, 0.f);
    BFLY(b1, b5, r2,  sg * r2);
    BFLY(b2, b6, 0.f, sg * 1.f);
    BFLY(b3, b7, -r2, sg * r2);
    BFLY(b0, b2, 1.f, 0.f);
    BFLY(b1, b3, 0.f, sg * 1.f);
    BFLY(b4, b6, 1.f, 0.f);
    BFLY(b5, b7, 0.f, sg * 1.f);
    BFLY(b0, b1, 1.f, 0.f);
    BFLY(b2, b3, 1.f, 0.f);
    BFLY(b4, b5, 1.f, 0.f);
    BFLY(b6, b7, 1.f, 0.f);
}

#define CTW(w) make_float2((w).x, -(w).y)

// Mid-twiddle stores via 16K table twM[t] = e^{-2pi i t/M}. rr,lo,hi < 128 so
// rr*lo < 16384 -- direct index, no mod, no sincosf (kills the spill-inducing
// libcall sites). Forward uses twM, inverse uses conj.
#define STW_FWD(var, rr) mp[sidx((rr), lo)] = cmul((var), twM[(rr) * lo])
#define STW_INV(var, bc) mp[sidx(hi, (bc))] = cmul((var), CTW(twM[(bc) * hi]))

// ---------------------------------------------------------------------------
// Forward four-step core on named scalars. On entry a0..a15 hold
// x[1024*n1 + 128*n2 + lo] for n1=0..15. On exit mp(hi=r, lo=s) = X[r+128*s],
// trailing barrier done.
// ---------------------------------------------------------------------------
__device__ __forceinline__ void fwd_core(float2* __restrict__ mp,
        const float2* __restrict__ twg, const float2* __restrict__ twM,
        const int lo, const int n2,
        float2 &a0, float2 &a1, float2 &a2, float2 &a3,
        float2 &a4, float2 &a5, float2 &a6, float2 &a7,
        float2 &a8, float2 &a9, float2 &a10, float2 &a11,
        float2 &a12, float2 &a13, float2 &a14, float2 &a15) {
    // ----- cols stage 1: FFT16 over n1, twiddle W_128^{n2*k1}, bitrev k1 -----
    fft16s<false>(a0, a1, a2, a3, a4, a5, a6, a7, a8, a9, a10, a11, a12, a13, a14, a15);
    mp[sidx(n2,       lo)] = a0;
    mp[sidx(64 + n2,  lo)] = cmul(a1,  twg[n2 * 8]);
    mp[sidx(32 + n2,  lo)] = cmul(a2,  twg[n2 * 4]);
    mp[sidx(96 + n2,  lo)] = cmul(a3,  twg[n2 * 12]);
    mp[sidx(16 + n2,  lo)] = cmul(a4,  twg[n2 * 2]);
    mp[sidx(80 + n2,  lo)] = cmul(a5,  twg[n2 * 10]);
    mp[sidx(48 + n2,  lo)] = cmul(a6,  twg[n2 * 6]);
    mp[sidx(112 + n2, lo)] = cmul(a7,  twg[n2 * 14]);
    mp[sidx(8 + n2,   lo)] = cmul(a8,  twg[n2 * 1]);
    mp[sidx(72 + n2,  lo)] = cmul(a9,  twg[n2 * 9]);
    mp[sidx(40 + n2,  lo)] = cmul(a10, twg[n2 * 5]);
    mp[sidx(104 + n2, lo)] = cmul(a11, twg[n2 * 13]);
    mp[sidx(24 + n2,  lo)] = cmul(a12, twg[n2 * 3]);
    mp[sidx(88 + n2,  lo)] = cmul(a13, twg[n2 * 11]);
    mp[sidx(56 + n2,  lo)] = cmul(a14, twg[n2 * 7]);
    mp[sidx(120 + n2, lo)] = cmul(a15, twg[n2 * 15]);
    __syncthreads();
    // ----- cols stage 2: FFT8 over n2, fold mid twiddle W_M^{r*lo} -----
    {
        float2 b0 = mp[sidx(8 * n2 + 0, lo)];
        float2 b1 = mp[sidx(8 * n2 + 1, lo)];
        float2 b2 = mp[sidx(8 * n2 + 2, lo)];
        float2 b3 = mp[sidx(8 * n2 + 3, lo)];
        float2 b4 = mp[sidx(8 * n2 + 4, lo)];
        float2 b5 = mp[sidx(8 * n2 + 5, lo)];
        float2 b6 = mp[sidx(8 * n2 + 6, lo)];
        float2 b7 = mp[sidx(8 * n2 + 7, lo)];
        float2 c0 = mp[sidx(8 * n2 + 64, lo)];
        float2 c1 = mp[sidx(8 * n2 + 65, lo)];
        float2 c2 = mp[sidx(8 * n2 + 66, lo)];
        float2 c3 = mp[sidx(8 * n2 + 67, lo)];
        float2 c4 = mp[sidx(8 * n2 + 68, lo)];
        float2 c5 = mp[sidx(8 * n2 + 69, lo)];
        float2 c6 = mp[sidx(8 * n2 + 70, lo)];
        float2 c7 = mp[sidx(8 * n2 + 71, lo)];
        __syncthreads();
        fft8s<false>(b0, b1, b2, b3, b4, b5, b6, b7);
        fft8s<false>(c0, c1, c2, c3, c4, c5, c6, c7);
        STW_FWD(b0, n2 + 0);  STW_FWD(b1, n2 + 64);
        STW_FWD(b2, n2 + 32); STW_FWD(b3, n2 + 96);
        STW_FWD(b4, n2 + 16); STW_FWD(b5, n2 + 80);
        STW_FWD(b6, n2 + 48); STW_FWD(b7, n2 + 112);
        STW_FWD(c0, n2 + 8);  STW_FWD(c1, n2 + 72);
        STW_FWD(c2, n2 + 40); STW_FWD(c3, n2 + 104);
        STW_FWD(c4, n2 + 24); STW_FWD(c5, n2 + 88);
        STW_FWD(c6, n2 + 56); STW_FWD(c7, n2 + 120);
    }
    __syncthreads();
    // ----- rows stage 1: FFT16 along lo, twiddle W_128^{n2*k1} -----
    const int hi = lo;
    a0  = mp[sidx(hi, n2)];
    a1  = mp[sidx(hi, 8 + n2)];
    a2  = mp[sidx(hi, 16 + n2)];
    a3  = mp[sidx(hi, 24 + n2)];
    a4  = mp[sidx(hi, 32 + n2)];
    a5  = mp[sidx(hi, 40 + n2)];
    a6  = mp[sidx(hi, 48 + n2)];
    a7  = mp[sidx(hi, 56 + n2)];
    a8  = mp[sidx(hi, 64 + n2)];
    a9  = mp[sidx(hi, 72 + n2)];
    a10 = mp[sidx(hi, 80 + n2)];
    a11 = mp[sidx(hi, 88 + n2)];
    a12 = mp[sidx(hi, 96 + n2)];
    a13 = mp[sidx(hi, 104 + n2)];
    a14 = mp[sidx(hi, 112 + n2)];
    a15 = mp[sidx(hi, 120 + n2)];
    fft16s<false>(a0, a1, a2, a3, a4, a5, a6, a7, a8, a9, a10, a11, a12, a13, a14, a15);
    mp[sidx(hi, n2)]       = a0;
    mp[sidx(hi, 64 + n2)]  = cmul(a1,  twg[n2 * 8]);
    mp[sidx(hi, 32 + n2)]  = cmul(a2,  twg[n2 * 4]);
    mp[sidx(hi, 96 + n2)]  = cmul(a3,  twg[n2 * 12]);
    mp[sidx(hi, 16 + n2)]  = cmul(a4,  twg[n2 * 2]);
    mp[sidx(hi, 80 + n2)]  = cmul(a5,  twg[n2 * 10]);
    mp[sidx(hi, 48 + n2)]  = cmul(a6,  twg[n2 * 6]);
    mp[sidx(hi, 112 + n2)] = cmul(a7,  twg[n2 * 14]);
    mp[sidx(hi, 8 + n2)]   = cmul(a8,  twg[n2 * 1]);
    mp[sidx(hi, 72 + n2)]  = cmul(a9,  twg[n2 * 9]);
    mp[sidx(hi, 40 + n2)]  = cmul(a10, twg[n2 * 5]);
    mp[sidx(hi, 104 + n2)] = cmul(a11, twg[n2 * 13]);
    mp[sidx(hi, 24 + n2)]  = cmul(a12, twg[n2 * 3]);
    mp[sidx(hi, 88 + n2)]  = cmul(a13, twg[n2 * 11]);
    mp[sidx(hi, 56 + n2)]  = cmul(a14, twg[n2 * 7]);
    mp[sidx(hi, 120 + n2)] = cmul(a15, twg[n2 * 15]);
    __syncthreads();
    // ----- rows stage 2: FFT8 over n2 (no extra twiddle) -----
    {
        float2 b0 = mp[sidx(hi, 8 * n2 + 0)];
        float2 b1 = mp[sidx(hi, 8 * n2 + 1)];
        float2 b2 = mp[sidx(hi, 8 * n2 + 2)];
        float2 b3 = mp[sidx(hi, 8 * n2 + 3)];
        float2 b4 = mp[sidx(hi, 8 * n2 + 4)];
        float2 b5 = mp[sidx(hi, 8 * n2 + 5)];
        float2 b6 = mp[sidx(hi, 8 * n2 + 6)];
        float2 b7 = mp[sidx(hi, 8 * n2 + 7)];
        float2 c0 = mp[sidx(hi, 8 * n2 + 64)];
        float2 c1 = mp[sidx(hi, 8 * n2 + 65)];
        float2 c2 = mp[sidx(hi, 8 * n2 + 66)];
        float2 c3 = mp[sidx(hi, 8 * n2 + 67)];
        float2 c4 = mp[sidx(hi, 8 * n2 + 68)];
        float2 c5 = mp[sidx(hi, 8 * n2 + 69)];
        float2 c6 = mp[sidx(hi, 8 * n2 + 70)];
        float2 c7 = mp[sidx(hi, 8 * n2 + 71)];
        __syncthreads();
        fft8s<false>(b0, b1, b2, b3, b4, b5, b6, b7);
        fft8s<false>(c0, c1, c2, c3, c4, c5, c6, c7);
        mp[sidx(hi, n2 + 0)]   = b0;
        mp[sidx(hi, n2 + 64)]  = b1;
        mp[sidx(hi, n2 + 32)]  = b2;
        mp[sidx(hi, n2 + 96)]  = b3;
        mp[sidx(hi, n2 + 16)]  = b4;
        mp[sidx(hi, n2 + 80)]  = b5;
        mp[sidx(hi, n2 + 48)]  = b6;
        mp[sidx(hi, n2 + 112)] = b7;
        mp[sidx(hi, n2 + 8)]   = c0;
        mp[sidx(hi, n2 + 72)]  = c1;
        mp[sidx(hi, n2 + 40)]  = c2;
        mp[sidx(hi, n2 + 104)] = c3;
        mp[sidx(hi, n2 + 24)]  = c4;
        mp[sidx(hi, n2 + 88)]  = c5;
        mp[sidx(hi, n2 + 56)]  = c6;
        mp[sidx(hi, n2 + 120)] = c7;
    }
    __syncthreads();
}

// ---------------------------------------------------------------------------
// K0: per-bin scan of G for nonzero head/tail block sizes (exact-0 padding).
// ---------------------------------------------------------------------------
__global__ void k0_scan(const float* __restrict__ G, int NL, int* __restrict__ hnh) {
    const int j = blockIdx.x;
    __shared__ int s_first, s_last;
    if (threadIdx.x == 0) { s_first = NL; s_last = -1; }
    __syncthreads();
    const float* Gj = G + (size_t)j * NL;
    for (int m = threadIdx.x; m < NL; m += blockDim.x) {
        if (Gj[m] == 0.0f) {
            atomicMin(&s_first, m);
            atomicMax(&s_last, m);
        }
    }
    __syncthreads();
    if (threadIdx.x == 0) {
        int h  = s_first;
        int nh = (s_last >= 0) ? (NL - 1 - s_last) : 0;
        hnh[2 * j]     = h;
        hnh[2 * j + 1] = nh;
    }
}

// ---------------------------------------------------------------------------
// K1: 525-point DFT per (n2, r), split 525 = 25 x 21 (Cooley-Tukey in LDS).
// ---------------------------------------------------------------------------
__global__ __launch_bounds__(TPB) void k1_dft525(const float* __restrict__ x,
                                                 float2* __restrict__ A) {
    const int n2 = blockIdx.x;
    const int r  = blockIdx.y;
    __shared__ float  xs[N1];
    __shared__ float2 ys[N1];
    __shared__ float2 w25[25];
    __shared__ float2 w21[21];
    const float* xr = x + (size_t)r * LS + n2;
    for (int t = threadIdx.x; t < N1; t += TPB) {
        xs[t] = xr[(size_t)t * N2];
    }
    if (threadIdx.x < 25) {
        float a = -TWO_PI_F * (float)threadIdx.x / 25.0f;
        float s, c; sincosf(a, &s, &c);
        w25[threadIdx.x] = make_float2(c, s);
    } else if (threadIdx.x >= 32 && threadIdx.x < 53) {
        int k = threadIdx.x - 32;
        float a = -TWO_PI_F * (float)k / 21.0f;
        float s, c; sincosf(a, &s, &c);
        w21[k] = make_float2(c, s);
    }
    __syncthreads();
    for (int i = threadIdx.x; i < N1; i += TPB) {
        int alpha = i % 25, b = i / 25;
        float re = 0.f, im = 0.f;
        int iw = 0, it = b;
        #pragma unroll
        for (int a = 0; a < 25; ++a) {
            float  v = xs[it];
            float2 w = w25[iw];
            re = fmaf(v, w.x, re);
            im = fmaf(v, w.y, im);
            it += 21;
            iw += alpha; if (iw >= 25) iw -= 25;
        }
        float ang = -TWO_PI_F * (float)(b * alpha) / (float)N1;
        float s, c; sincosf(ang, &s, &c);
        ys[i] = make_float2(re * c - im * s, re * s + im * c);
    }
    __syncthreads();
    for (int k = threadIdx.x; k < N1; k += TPB) {
        int alpha = k % 25, beta = k / 25;
        float re = 0.f, im = 0.f;
        int iw = 0, iy = alpha;
        #pragma unroll
        for (int b = 0; b < 21; ++b) {
            float2 v = ys[iy];
            float2 w = w21[iw];
            re = fmaf(v.x, w.x, re); re = fmaf(-v.y, w.y, re);
            im = fmaf(v.x, w.y, im); im = fmaf( v.y, w.x, im);
            iy += 25;
            iw += beta; if (iw >= 21) iw -= 21;
        }
        float ang = -TWO_PI_F * (float)(k * n2) / (float)LS;
        float s, c; sincosf(ang, &s, &c);
        A[((size_t)r * N1 + k) * N2 + n2] = make_float2(re * c - im * s, re * s + im * c);
    }
}

// ---------------------------------------------------------------------------
// K2: 504-point DFT per (k1, r), split 504 = 21 x 24 (Cooley-Tukey in LDS).
// ---------------------------------------------------------------------------
__global__ __launch_bounds__(TPB) void k2_dft504(float2* __restrict__ A) {
    const int k1 = blockIdx.x;
    const int r  = blockIdx.y;
    __shared__ float2 as[N2];
    __shared__ float2 ys[N2];
    __shared__ float2 w21[21];
    __shared__ float2 w24[24];
    float2* row = A + ((size_t)r * N1 + k1) * N2;
    for (int t = threadIdx.x; t < N2; t += TPB) as[t] = row[t];
    if (threadIdx.x < 21) {
        float a = -TWO_PI_F * (float)threadIdx.x / 21.0f;
        float s, c; sincosf(a, &s, &c);
        w21[threadIdx.x] = make_float2(c, s);
    } else if (threadIdx.x >= 32 && threadIdx.x < 56) {
        int k = threadIdx.x - 32;
        float a = -TWO_PI_F * (float)k / 24.0f;
        float s, c; sincosf(a, &s, &c);
        w24[k] = make_float2(c, s);
    }
    __syncthreads();
    for (int i = threadIdx.x; i < N2; i += TPB) {
        int alpha = i % 21, b = i / 21;
        float re = 0.f, im = 0.f;
        int iw = 0, it = b;
        #pragma unroll
        for (int a = 0; a < 21; ++a) {
            float2 v = as[it];
            float2 w = w21[iw];
            re = fmaf(v.x, w.x, re); re = fmaf(-v.y, w.y, re);
            im = fmaf(v.x, w.y, im); im = fmaf( v.y, w.x, im);
            it += 24;
            iw += alpha; if (iw >= 21) iw -= 21;
        }
        float ang = -TWO_PI_F * (float)(b * alpha) / (float)N2;
        float s, c; sincosf(ang, &s, &c);
        ys[i] = make_float2(re * c - im * s, re * s + im * c);
    }
    __syncthreads();
    for (int k = threadIdx.x; k < N2; k += TPB) {
        int alpha = k % 21, beta = k / 21;
        float re = 0.f, im = 0.f;
        int iw = 0, iy = alpha;
        #pragma unroll
        for (int b = 0; b < 24; ++b) {
            float2 v = ys[iy];
            float2 w = w24[iw];
            re = fmaf(v.x, w.x, re); re = fmaf(-v.y, w.y, re);
            im = fmaf(v.x, w.y, im); im = fmaf( v.y, w.x, im);
            iy += 21;
            iw += beta; if (iw >= 24) iw -= 24;
        }
        row[k] = make_float2(re, im);
    }
}

// ---------------------------------------------------------------------------
// K_SETUP: chirp tables + W_128 table + 16K-entry W_M table.
// ---------------------------------------------------------------------------
__global__ void k_setup(float2* __restrict__ kc, float2* __restrict__ bchirp,
                        float2* __restrict__ twg, float2* __restrict__ twM, int NL) {
    int t = blockIdx.x * blockDim.x + threadIdx.x;
    long long twoNL = 2LL * NL;
    if (t < M_FFT) {
        long long d = 0; bool act = false;
        if (t < NL)              { d = t;        act = true; }
        else if (t > M_FFT - NL) { d = t - M_FFT; act = true; }
        float2 v = make_float2(0.f, 0.f);
        if (act) {
            long long ph = (d * d) % twoNL;
            float th = -PI_F * (float)ph / (float)NL;
            float s, c; sincosf(th, &s, &c);
            v = make_float2(c, s);
        }
        kc[t] = v;
    } else {
        int n = t - M_FFT;
        if (n < NL) {
            long long ph = ((long long)n * n) % twoNL;
            float th = PI_F * (float)ph / (float)NL;
            float s, c; sincosf(th, &s, &c);
            bchirp[n] = make_float2(c, s);
        } else if (n < NL + 128) {
            int q = n - NL;
            float th = -TWO_PI_F * (float)q / 128.0f;
            float s, c; sincosf(th, &s, &c);
            twg[q] = make_float2(c, s);
        } else if (n < NL + 128 + M_FFT) {
            int q = n - NL - 128;
            float th = -TWO_PI_F * (float)q / (float)M_FFT;
            float s, c; sincosf(th, &s, &c);
            twM[q] = make_float2(c, s);
        }
    }
}

// ---------------------------------------------------------------------------
// K_KF: one block. KFt[s*128 + r] = FFT16k(kc)[r + 128*s]  (transposed store
// so k_fused's inverse-row loads are coalesced).
// ---------------------------------------------------------------------------
__global__ __launch_bounds__(TPF)
__attribute__((amdgpu_waves_per_eu(4, 4)))
void k_kf(const float2* __restrict__ kc, const float2* __restrict__ twg,
          const float2* __restrict__ twM, float2* __restrict__ KFt) {
    extern __shared__ float2 mp[];
    const int tid = threadIdx.x;
    const int lo = tid & 127, n2 = tid >> 7;
    float2 a0  = kc[tid];
    float2 a1  = kc[1024 + tid];
    float2 a2  = kc[2048 + tid];
    float2 a3  = kc[3072 + tid];
    float2 a4  = kc[4096 + tid];
    float2 a5  = kc[5120 + tid];
    float2 a6  = kc[6144 + tid];
    float2 a7  = kc[7168 + tid];
    float2 a8  = kc[8192 + tid];
    float2 a9  = kc[9216 + tid];
    float2 a10 = kc[10240 + tid];
    float2 a11 = kc[11264 + tid];
    float2 a12 = kc[12288 + tid];
    float2 a13 = kc[13312 + tid];
    float2 a14 = kc[14336 + tid];
    float2 a15 = kc[15360 + tid];
    fwd_core(mp, twg, twM, lo, n2, a0, a1, a2, a3, a4, a5, a6, a7,
             a8, a9, a10, a11, a12, a13, a14, a15);
    for (int i = tid; i < M_FFT; i += TPF) {
        int hh = i >> 7, ll = i & 127;
        KFt[(size_t)ll * 128 + hh] = mp[sidx(hh, ll)];
    }
}

// ---------------------------------------------------------------------------
// K_FUSED: one transform per block; gather -> fwd -> xKF -> inv -> out.
// All FFT state in named scalar registers; LDS only between stages.
// No transcendentals anywhere (table-driven) -> no libcall spill pressure.
// ---------------------------------------------------------------------------
#define GATH(var, I) do {                                                     \
    (var) = make_float2(0.f, 0.f);                                            \
    const int i_ = (I);                                                       \
    if (i_ < h || (i_ >= tail0 && i_ < NL)) {                                 \
        int k_ = ij[i_];                                                      \
        float2 f_ = Ar[(size_t)(k_ % N1) * N2 + (k_ / N1)];                   \
        float  g_ = Gj[i_];                                                   \
        (var) = cmul(make_float2(f_.x * g_, f_.y * g_), bchirp[i_]);          \
    }                                                                         \
} while (0)

#define FINST(var, acol) do {                                                 \
    const int n_ = 128 * (acol) + lo;                                         \
    if (n_ < NL) {                                                            \
        float2 y_ = cmul((var), bchirp[n_]);                                  \
        outv[n_] = make_float2(y_.x * sc, y_.y * sc);                         \
    }                                                                         \
} while (0)

__global__ __launch_bounds__(TPF)
__attribute__((amdgpu_waves_per_eu(4, 4)))
void k_fused(const float* __restrict__ Gm,
        const int* __restrict__ idxp, const float2* __restrict__ A,
        const int* __restrict__ hnh, const float2* __restrict__ bchirp,
        const float2* __restrict__ KFt, const float2* __restrict__ twg,
        const float2* __restrict__ twM,
        float2* __restrict__ out, int NB, int NL) {
    extern __shared__ float2 mp[];
    const int tid = threadIdx.x;
    const int lo = tid & 127, n2 = tid >> 7;
    const int vg = blockIdx.x;
    const int rr_ = vg / NB, jb = vg % NB;
    const int h = hnh[2 * jb], nh = hnh[2 * jb + 1];
    const int tail0 = NL - nh;
    const float* Gj = Gm + (size_t)jb * NL;
    const int*   ij = idxp + (size_t)jb * NL;
    const float2* Ar = A + (size_t)rr_ * LS;

    // ===== forward (gather fused into stage-1 loads) =====
    float2 a0, a1, a2, a3, a4, a5, a6, a7, a8, a9, a10, a11, a12, a13, a14, a15;
    GATH(a0, tid);
    GATH(a1, 1024 + tid);
    GATH(a2, 2048 + tid);
    GATH(a3, 3072 + tid);
    GATH(a4, 4096 + tid);
    GATH(a5, 5120 + tid);
    GATH(a6, 6144 + tid);
    GATH(a7, 7168 + tid);
    GATH(a8, 8192 + tid);
    GATH(a9, 9216 + tid);
    GATH(a10, 10240 + tid);
    GATH(a11, 11264 + tid);
    GATH(a12, 12288 + tid);
    GATH(a13, 13312 + tid);
    GATH(a14, 14336 + tid);
    GATH(a15, 15360 + tid);
    fwd_core(mp, twg, twM, lo, n2, a0, a1, a2, a3, a4, a5, a6, a7,
             a8, a9, a10, a11, a12, a13, a14, a15);
    // mp(r, s) = X[r + 128*s]

    const int hi = lo;
    // ===== inverse rows stage 1: xKF^T at load, IFFT16, conj twiddle =====
    a0  = cmul(mp[sidx(hi, n2)],       KFt[(size_t)(n2) * 128 + hi]);
    a1  = cmul(mp[sidx(hi, 8 + n2)],   KFt[(size_t)(8 + n2) * 128 + hi]);
    a2  = cmul(mp[sidx(hi, 16 + n2)],  KFt[(size_t)(16 + n2) * 128 + hi]);
    a3  = cmul(mp[sidx(hi, 24 + n2)],  KFt[(size_t)(24 + n2) * 128 + hi]);
    a4  = cmul(mp[sidx(hi, 32 + n2)],  KFt[(size_t)(32 + n2) * 128 + hi]);
    a5  = cmul(mp[sidx(hi, 40 + n2)],  KFt[(size_t)(40 + n2) * 128 + hi]);
    a6  = cmul(mp[sidx(hi, 48 + n2)],  KFt[(size_t)(48 + n2) * 128 + hi]);
    a7  = cmul(mp[sidx(hi, 56 + n2)],  KFt[(size_t)(56 + n2) * 128 + hi]);
    a8  = cmul(mp[sidx(hi, 64 + n2)],  KFt[(size_t)(64 + n2) * 128 + hi]);
    a9  = cmul(mp[sidx(hi, 72 + n2)],  KFt[(size_t)(72 + n2) * 128 + hi]);
    a10 = cmul(mp[sidx(hi, 80 + n2)],  KFt[(size_t)(80 + n2) * 128 + hi]);
    a11 = cmul(mp[sidx(hi, 88 + n2)],  KFt[(size_t)(88 + n2) * 128 + hi]);
    a12 = cmul(mp[sidx(hi, 96 + n2)],  KFt[(size_t)(96 + n2) * 128 + hi]);
    a13 = cmul(mp[sidx(hi, 104 + n2)], KFt[(size_t)(104 + n2) * 128 + hi]);
    a14 = cmul(mp[sidx(hi, 112 + n2)], KFt[(size_t)(112 + n2) * 128 + hi]);
    a15 = cmul(mp[sidx(hi, 120 + n2)], KFt[(size_t)(120 + n2) * 128 + hi]);
    fft16s<true>(a0, a1, a2, a3, a4, a5, a6, a7, a8, a9, a10, a11, a12, a13, a14, a15);
    mp[sidx(hi, n2)]       = a0;
    mp[sidx(hi, 64 + n2)]  = cmul(a1,  CTW(twg[n2 * 8]));
    mp[sidx(hi, 32 + n2)]  = cmul(a2,  CTW(twg[n2 * 4]));
    mp[sidx(hi, 96 + n2)]  = cmul(a3,  CTW(twg[n2 * 12]));
    mp[sidx(hi, 16 + n2)]  = cmul(a4,  CTW(twg[n2 * 2]));
    mp[sidx(hi, 80 + n2)]  = cmul(a5,  CTW(twg[n2 * 10]));
    mp[sidx(hi, 48 + n2)]  = cmul(a6,  CTW(twg[n2 * 6]));
    mp[sidx(hi, 112 + n2)] = cmul(a7,  CTW(twg[n2 * 14]));
    mp[sidx(hi, 8 + n2)]   = cmul(a8,  CTW(twg[n2 * 1]));
    mp[sidx(hi, 72 + n2)]  = cmul(a9,  CTW(twg[n2 * 9]));
    mp[sidx(hi, 40 + n2)]  = cmul(a10, CTW(twg[n2 * 5]));
    mp[sidx(hi, 104 + n2)] = cmul(a11, CTW(twg[n2 * 13]));
    mp[sidx(hi, 24 + n2)]  = cmul(a12, CTW(twg[n2 * 3]));
    mp[sidx(hi, 88 + n2)]  = cmul(a13, CTW(twg[n2 * 11]));
    mp[sidx(hi, 56 + n2)]  = cmul(a14, CTW(twg[n2 * 7]));
    mp[sidx(hi, 120 + n2)] = cmul(a15, CTW(twg[n2 * 15]));
    __syncthreads();
    // ===== inverse rows stage 2: IFFT8, fold inv mid twiddle =====
    {
        float2 b0 = mp[sidx(hi, 8 * n2 + 0)];
        float2 b1 = mp[sidx(hi, 8 * n2 + 1)];
        float2 b2 = mp[sidx(hi, 8 * n2 + 2)];
        float2 b3 = mp[sidx(hi, 8 * n2 + 3)];
        float2 b4 = mp[sidx(hi, 8 * n2 + 4)];
        float2 b5 = mp[sidx(hi, 8 * n2 + 5)];
        float2 b6 = mp[sidx(hi, 8 * n2 + 6)];
        float2 b7 = mp[sidx(hi, 8 * n2 + 7)];
        float2 c0 = mp[sidx(hi, 8 * n2 + 64)];
        float2 c1 = mp[sidx(hi, 8 * n2 + 65)];
        float2 c2 = mp[sidx(hi, 8 * n2 + 66)];
        float2 c3 = mp[sidx(hi, 8 * n2 + 67)];
        float2 c4 = mp[sidx(hi, 8 * n2 + 68)];
        float2 c5 = mp[sidx(hi, 8 * n2 + 69)];
        float2 c6 = mp[sidx(hi, 8 * n2 + 70)];
        float2 c7 = mp[sidx(hi, 8 * n2 + 71)];
        __syncthreads();
        fft8s<true>(b0, b1, b2, b3, b4, b5, b6, b7);
        fft8s<true>(c0, c1, c2, c3, c4, c5, c6, c7);
        STW_INV(b0, n2 + 0);  STW_INV(b1, n2 + 64);
        STW_INV(b2, n2 + 32); STW_INV(b3, n2 + 96);
        STW_INV(b4, n2 + 16); STW_INV(b5, n2 + 80);
        STW_INV(b6, n2 + 48); STW_INV(b7, n2 + 112);
        STW_INV(c0, n2 + 8);  STW_INV(c1, n2 + 72);
        STW_INV(c2, n2 + 40); STW_INV(c3, n2 + 104);
        STW_INV(c4, n2 + 24); STW_INV(c5, n2 + 88);
        STW_INV(c6, n2 + 56); STW_INV(c7, n2 + 120);
    }
    __syncthreads();
    // ===== inverse cols stage 1: IFFT16 over hi, conj twiddle =====
    a0  = mp[sidx(n2, lo)];
    a1  = mp[sidx(8 + n2, lo)];
    a2  = mp[sidx(16 + n2, lo)];
    a3  = mp[sidx(24 + n2, lo)];
    a4  = mp[sidx(32 + n2, lo)];
    a5  = mp[sidx(40 + n2, lo)];
    a6  = mp[sidx(48 + n2, lo)];
    a7  = mp[sidx(56 + n2, lo)];
    a8  = mp[sidx(64 + n2, lo)];
    a9  = mp[sidx(72 + n2, lo)];
    a10 = mp[sidx(80 + n2, lo)];
    a11 = mp[sidx(88 + n2, lo)];
    a12 = mp[sidx(96 + n2, lo)];
    a13 = mp[sidx(104 + n2, lo)];
    a14 = mp[sidx(112 + n2, lo)];
    a15 = mp[sidx(120 + n2, lo)];
    fft16s<true>(a0, a1, a2, a3, a4, a5, a6, a7, a8, a9, a10, a11, a12, a13, a14, a15);
    mp[sidx(n2, lo)]       = a0;
    mp[sidx(64 + n2, lo)]  = cmul(a1,  CTW(twg[n2 * 8]));
    mp[sidx(32 + n2, lo)]  = cmul(a2,  CTW(twg[n2 * 4]));
    mp[sidx(96 + n2, lo)]  = cmul(a3,  CTW(twg[n2 * 12]));
    mp[sidx(16 + n2, lo)]  = cmul(a4,  CTW(twg[n2 * 2]));
    mp[sidx(80 + n2, lo)]  = cmul(a5,  CTW(twg[n2 * 10]));
    mp[sidx(48 + n2, lo)]  = cmul(a6,  CTW(twg[n2 * 6]));
    mp[sidx(112 + n2, lo)] = cmul(a7,  CTW(twg[n2 * 14]));
    mp[sidx(8 + n2, lo)]   = cmul(a8,  CTW(twg[n2 * 1]));
    mp[sidx(72 + n2, lo)]  = cmul(a9,  CTW(twg[n2 * 9]));
    mp[sidx(40 + n2, lo)]  = cmul(a10, CTW(twg[n2 * 5]));
    mp[sidx(104 + n2, lo)] = cmul(a11, CTW(twg[n2 * 13]));
    mp[sidx(24 + n2, lo)]  = cmul(a12, CTW(twg[n2 * 3]));
    mp[sidx(88 + n2, lo)]  = cmul(a13, CTW(twg[n2 * 11]));
    mp[sidx(56 + n2, lo)]  = cmul(a14, CTW(twg[n2 * 7]));
    mp[sidx(120 + n2, lo)] = cmul(a15, CTW(twg[n2 * 15]));
    __syncthreads();
    // ===== inverse cols stage 2: IFFT8 -> y[128*a + lo] -> global out =====
    {
        float2 b0 = mp[sidx(8 * n2 + 0, lo)];
        float2 b1 = mp[sidx(8 * n2 + 1, lo)];
        float2 b2 = mp[sidx(8 * n2 + 2, lo)];
        float2 b3 = mp[sidx(8 * n2 + 3, lo)];
        float2 b4 = mp[sidx(8 * n2 + 4, lo)];
        float2 b5 = mp[sidx(8 * n2 + 5, lo)];
        float2 b6 = mp[sidx(8 * n2 + 6, lo)];
        float2 b7 = mp[sidx(8 * n2 + 7, lo)];
        float2 c0 = mp[sidx(8 * n2 + 64, lo)];
        float2 c1 = mp[sidx(8 * n2 + 65, lo)];
        float2 c2 = mp[sidx(8 * n2 + 66, lo)];
        float2 c3 = mp[sidx(8 * n2 + 67, lo)];
        float2 c4 = mp[sidx(8 * n2 + 68, lo)];
        float2 c5 = mp[sidx(8 * n2 + 69, lo)];
        float2 c6 = mp[sidx(8 * n2 + 70, lo)];
        float2 c7 = mp[sidx(8 * n2 + 71, lo)];
        fft8s<true>(b0, b1, b2, b3, b4, b5, b6, b7);
        fft8s<true>(c0, c1, c2, c3, c4, c5, c6, c7);
        const float sc = 100.0f / ((float)NL * (float)M_FFT);
        float2* outv = out + (size_t)vg * NL;
        FINST(b0, n2 + 0);  FINST(b1, n2 + 64);
        FINST(b2, n2 + 32); FINST(b3, n2 + 96);
        FINST(b4, n2 + 16); FINST(b5, n2 + 80);
        FINST(b6, n2 + 48); FINST(b7, n2 + 112);
        FINST(c0, n2 + 8);  FINST(c1, n2 + 72);
        FINST(c2, n2 + 40); FINST(c3, n2 + 104);
        FINST(c4, n2 + 24); FINST(c5, n2 + 88);
        FINST(c6, n2 + 56); FINST(c7, n2 + 120);
    }
}

// ---------------------------------------------------------------------------
// Legacy direct zoom-IDFT — fallback if NL too large or ws too small.
// ---------------------------------------------------------------------------
__global__ __launch_bounds__(TPB) void k3_idft(const float* __restrict__ G,
                                               const int*  __restrict__ idxp,
                                               const float2* __restrict__ FT,
                                               const int*  __restrict__ hnh,
                                               float2* __restrict__ out,
                                               int NB, int NL) {
    extern __shared__ float2 cls[];
    const int j = blockIdx.x;
    const int r = blockIdx.y;
    const int h  = hnh[2 * j];
    const int nh = hnh[2 * j + 1];
    const int Lg = h + nh;
    const float* Gj = G    + (size_t)j * NL;
    const int*   ij = idxp + (size_t)j * NL;

    for (int t = threadIdx.x; t < Lg; t += TPB) {
        int m = (t < h) ? t : (NL - nh + (t - h));
        int k = ij[m];
        float2 f = FT[((size_t)r * N1 + (k % N1)) * N2 + (k / N1)];
        float  g = Gj[m];
        cls[t] = make_float2(f.x * g, f.y * g);
    }
    __syncthreads();

    const float scale = 100.0f / (float)NL;
    const float w0 = TWO_PI_F / (float)NL;
    float2* outr = out + ((size_t)r * NB + j) * NL;

    for (int n_base = 0; n_base < NL; n_base += 4 * TPB) {
        int   n[4];
        float are[4], aim[4], twr[4], twi[4], str[4], sti[4];
        #pragma unroll
        for (int u = 0; u < 4; ++u) {
            n[u] = n_base + u * TPB + (int)threadIdx.x;
            are[u] = 0.f; aim[u] = 0.f;
            float s, c; sincosf(w0 * (float)(n[u] % NL), &s, &c);
            str[u] = c; sti[u] = s;
            twr[u] = 1.f; twi[u] = 0.f;
        }
        for (int t = 0; t < h; ++t) {
            if ((t & 255) == 0) {
                #pragma unroll
                for (int u = 0; u < 4; ++u) {
                    int mm = (int)(((long long)t * (long long)n[u]) % NL);
                    float s, c; sincosf(w0 * (float)mm, &s, &c);
                    twr[u] = c; twi[u] = s;
                }
            }
            float2 cv = cls[t];
            #pragma unroll
            for (int u = 0; u < 4; ++u) {
                are[u] = fmaf(cv.x, twr[u], are[u]);
                are[u] = fmaf(-cv.y, twi[u], are[u]);
                aim[u] = fmaf(cv.x, twi[u], aim[u]);
                aim[u] = fmaf(cv.y, twr[u], aim[u]);
                float nr = twr[u] * str[u] - twi[u] * sti[u];
                float ni = twr[u] * sti[u] + twi[u] * str[u];
                twr[u] = nr; twi[u] = ni;
            }
        }
        const int m0 = NL - nh;
        for (int t = 0; t < nh; ++t) {
            if ((t & 255) == 0) {
                #pragma unroll
                for (int u = 0; u < 4; ++u) {
                    int mm = (int)(((long long)(m0 + t) * (long long)n[u]) % NL);
                    float s, c; sincosf(w0 * (float)mm, &s, &c);
                    twr[u] = c; twi[u] = s;
                }
            }
            float2 cv = cls[h + t];
            #pragma unroll
            for (int u = 0; u < 4; ++u) {
                are[u] = fmaf(cv.x, twr[u], are[u]);
                are[u] = fmaf(-cv.y, twi[u], are[u]);
                aim[u] = fmaf(cv.x, twi[u], aim[u]);
                aim[u] = fmaf(cv.y, twr[u], aim[u]);
                float nr = twr[u] * str[u] - twi[u] * sti[u];
                float ni = twr[u] * sti[u] + twi[u] * str[u];
                twr[u] = nr; twi[u] = ni;
            }
        }
        #pragma unroll
        for (int u = 0; u < 4; ++u) {
            if (n[u] < NL) outr[n[u]] = make_float2(are[u] * scale, aim[u] * scale);
        }
    }
}

// ---------------------------------------------------------------------------
static inline size_t align256(size_t x) { return (x + 255) & ~(size_t)255; }

extern "C" void kernel_launch(void* const* d_in, const int* in_sizes, int n_in,
                              void* d_out, int out_size, void* d_ws, size_t ws_size,
                              hipStream_t stream) {
    const float* x   = (const float*)d_in[0];
    const float* Gm  = (const float*)d_in[1];
    const int*   idx = (const int*)d_in[2];
    float2*      out = (float2*)d_out;

    const int p  = in_sizes[1];
    const int NB = (p % 114 == 0) ? 114 : 115;
    const int NL = p / NB;
    const int B  = NB * ROWS;

    // ws layout: hnh | bchirp | twg(128) | twM(16384) | kc | KFt | A
    size_t hnh_off    = 0;
    size_t bchirp_off = align256(hnh_off + 2048);
    size_t twg_off    = align256(bchirp_off + (size_t)NL * 8);
    size_t twM_off    = align256(twg_off + 128 * 8);
    size_t kc_off     = align256(twM_off + (size_t)M_FFT * 8);
    size_t kft_off    = align256(kc_off + (size_t)M_FFT * 8);
    size_t A_off      = align256(kft_off + (size_t)M_FFT * 8);
    size_t need       = A_off + (size_t)ROWS * LS * 8;

    int*    hnh    = (int*)((char*)d_ws + hnh_off);
    float2* bchirp = (float2*)((char*)d_ws + bchirp_off);
    float2* twg    = (float2*)((char*)d_ws + twg_off);
    float2* twM    = (float2*)((char*)d_ws + twM_off);
    float2* kc     = (float2*)((char*)d_ws + kc_off);
    float2* KFt    = (float2*)((char*)d_ws + kft_off);
    float2* A      = (float2*)((char*)d_ws + A_off);

    k0_scan<<<dim3(NB), TPB, 0, stream>>>(Gm, NL, hnh);
    k1_dft525<<<dim3(N2, ROWS), TPB, 0, stream>>>(x, A);
    k2_dft504<<<dim3(N1, ROWS), TPB, 0, stream>>>(A);

    const bool fused_ok = (2 * NL - 1 <= M_FFT) && (need <= ws_size);
    if (fused_ok) {
        (void)hipFuncSetAttribute((const void*)k_fused,
                                  hipFuncAttributeMaxDynamicSharedMemorySize,
                                  M_FFT * (int)sizeof(float2));
        (void)hipFuncSetAttribute((const void*)k_kf,
                                  hipFuncAttributeMaxDynamicSharedMemorySize,
                                  M_FFT * (int)sizeof(float2));
        int setup_blocks = (2 * M_FFT + NL + 128 + TPB - 1) / TPB;
        k_setup<<<dim3(setup_blocks), TPB, 0, stream>>>(kc, bchirp, twg, twM, NL);
        k_kf<<<dim3(1), TPF, (size_t)M_FFT * sizeof(float2), stream>>>(kc, twg, twM, KFt);
        k_fused<<<dim3(B), TPF, (size_t)M_FFT * sizeof(float2), stream>>>(
            Gm, idx, A, hnh, bchirp, KFt, twg, twM, out, NB, NL);
    } else {
        k3_idft<<<dim3(NB, ROWS), TPB, (size_t)NL * sizeof(float2), stream>>>(
            Gm, idx, A, hnh, out, NB, NL);
    }
}

// Round 6
// 1735.013 us; speedup vs baseline: 1.0015x; 1.0015x over previous
//
#include <hip/hip_runtime.h>

#define TPB 256
#define TPF 1024
constexpr int LS = 264600;          // 6.0 s * 44100 Hz
constexpr int N1 = 525;             // LS = N1 * N2
constexpr int N2 = 504;
constexpr int ROWS = 32;            // S*C = 16*2
constexpr int M_FFT = 16384;        // Bluestein conv length >= 2*NL-1 (NL<=8192)
constexpr float TWO_PI_F = 6.28318530717958647692f;
constexpr float PI_F     = 3.14159265358979323846f;

__device__ __forceinline__ float2 cmul(float2 a, float2 b) {
    return make_float2(a.x * b.x - a.y * b.y, a.x * b.y + a.y * b.x);
}
// XOR-swizzled LDS index for the 128x128 array.
__device__ __forceinline__ int sidx(int hi, int lo) {
    return (hi << 7) + (lo ^ (hi & 15));
}

// ---------------------------------------------------------------------------
// Register FFT networks on NAMED scalars (no arrays -> guaranteed VGPRs).
// DIF, natural in, bit-reversed out. Twiddles are compile-time immediates.
// ---------------------------------------------------------------------------
#define BFLY(u, w, C, S) do {                       \
    float dx_ = (u).x - (w).x, dy_ = (u).y - (w).y; \
    (u).x += (w).x; (u).y += (w).y;                 \
    (w).x = dx_ * (C) - dy_ * (S);                  \
    (w).y = dx_ * (S) + dy_ * (C);                  \
} while (0)

template<bool INV>
__device__ __forceinline__ void fft16s(float2 &a0, float2 &a1, float2 &a2, float2 &a3,
                                       float2 &a4, float2 &a5, float2 &a6, float2 &a7,
                                       float2 &a8, float2 &a9, float2 &a10, float2 &a11,
                                       float2 &a12, float2 &a13, float2 &a14, float2 &a15) {
    constexpr float c1 = 0.92387953251128674f;
    constexpr float s1 = 0.38268343236508977f;
    constexpr float r2 = 0.70710678118654752f;
    const float sg = INV ? 1.f : -1.f;
    // span 8 (ti = j)
    BFLY(a0, a8,  1.f, 0.f);
    BFLY(a1, a9,  c1,  sg * s1);
    BFLY(a2, a10, r2,  sg * r2);
    BFLY(a3, a11, s1,  sg * c1);
    BFLY(a4, a12, 0.f, sg * 1.f);
    BFLY(a5, a13, -s1, sg * c1);
    BFLY(a6, a14, -r2, sg * r2);
    BFLY(a7, a15, -c1, sg * s1);
    // span 4 (ti = 2j)
    BFLY(a0, a4,  1.f, 0.f);
    BFLY(a1, a5,  r2,  sg * r2);
    BFLY(a2, a6,  0.f, sg * 1.f);
    BFLY(a3, a7,  -r2, sg * r2);
    BFLY(a8, a12, 1.f, 0.f);
    BFLY(a9, a13, r2,  sg * r2);
    BFLY(a10, a14, 0.f, sg * 1.f);
    BFLY(a11, a15, -r2, sg * r2);
    // span 2 (ti = 4j)
    BFLY(a0, a2,  1.f, 0.f);
    BFLY(a1, a3,  0.f, sg * 1.f);
    BFLY(a4, a6,  1.f, 0.f);
    BFLY(a5, a7,  0.f, sg * 1.f);
    BFLY(a8, a10, 1.f, 0.f);
    BFLY(a9, a11, 0.f, sg * 1.f);
    BFLY(a12, a14, 1.f, 0.f);
    BFLY(a13, a15, 0.f, sg * 1.f);
    // span 1
    BFLY(a0, a1,  1.f, 0.f);
    BFLY(a2, a3,  1.f, 0.f);
    BFLY(a4, a5,  1.f, 0.f);
    BFLY(a6, a7,  1.f, 0.f);
    BFLY(a8, a9,  1.f, 0.f);
    BFLY(a10, a11, 1.f, 0.f);
    BFLY(a12, a13, 1.f, 0.f);
    BFLY(a14, a15, 1.f, 0.f);
}

template<bool INV>
__device__ __forceinline__ void fft8s(float2 &b0, float2 &b1, float2 &b2, float2 &b3,
                                      float2 &b4, float2 &b5, float2 &b6, float2 &b7) {
    constexpr float r2 = 0.70710678118654752f;
    const float sg = INV ? 1.f : -1.f;
    BFLY(b0, b4, 1.f, 0.f);
    BFLY(b1, b5, r2,  sg * r2);
    BFLY(b2, b6, 0.f, sg * 1.f);
    BFLY(b3, b7, -r2, sg * r2);
    BFLY(b0, b2, 1.f, 0.f);
    BFLY(b1, b3, 0.f, sg * 1.f);
    BFLY(b4, b6, 1.f, 0.f);
    BFLY(b5, b7, 0.f, sg * 1.f);
    BFLY(b0, b1, 1.f, 0.f);
    BFLY(b2, b3, 1.f, 0.f);
    BFLY(b4, b5, 1.f, 0.f);
    BFLY(b6, b7, 1.f, 0.f);
}

#define CTW(w) make_float2((w).x, -(w).y)

// Mid-twiddle stores via 16K table twM[t] = e^{-2pi i t/M}. rr,lo,hi < 128 so
// rr*lo < 16384 -- direct index, no sincosf. Forward = twM, inverse = conj.
#define STW_FWD(var, rr) mp[sidx((rr), lo)] = cmul((var), twM[(rr) * lo])
#define STW_INV(var, bc) mp[sidx(hi, (bc))] = cmul((var), CTW(twM[(bc) * hi]))

// ---------------------------------------------------------------------------
// Forward four-step core. PRECONDITION: mp[sidx(i>>7, i&127)] holds input
// element x[i] (natural layout); an internal barrier orders that staging.
// On exit mp(hi=r, lo=s) = X[r + 128*s], trailing barrier done.
// Per-thread live set stays <= 16 float2 + temps (fits 128-VGPR budget).
// ---------------------------------------------------------------------------
__device__ __forceinline__ void fwd_core(float2* __restrict__ mp,
        const float2* __restrict__ twg, const float2* __restrict__ twM,
        const int lo, const int n2) {
    __syncthreads();                 // staging -> stage-1 reads
    // ----- cols stage 1: FFT16 over n1 (own 16 slots: read, FFT, write) -----
    float2 a0  = mp[sidx(n2,       lo)];
    float2 a1  = mp[sidx(8 + n2,   lo)];
    float2 a2  = mp[sidx(16 + n2,  lo)];
    float2 a3  = mp[sidx(24 + n2,  lo)];
    float2 a4  = mp[sidx(32 + n2,  lo)];
    float2 a5  = mp[sidx(40 + n2,  lo)];
    float2 a6  = mp[sidx(48 + n2,  lo)];
    float2 a7  = mp[sidx(56 + n2,  lo)];
    float2 a8  = mp[sidx(64 + n2,  lo)];
    float2 a9  = mp[sidx(72 + n2,  lo)];
    float2 a10 = mp[sidx(80 + n2,  lo)];
    float2 a11 = mp[sidx(88 + n2,  lo)];
    float2 a12 = mp[sidx(96 + n2,  lo)];
    float2 a13 = mp[sidx(104 + n2, lo)];
    float2 a14 = mp[sidx(112 + n2, lo)];
    float2 a15 = mp[sidx(120 + n2, lo)];
    fft16s<false>(a0, a1, a2, a3, a4, a5, a6, a7, a8, a9, a10, a11, a12, a13, a14, a15);
    mp[sidx(n2,       lo)] = a0;
    mp[sidx(64 + n2,  lo)] = cmul(a1,  twg[n2 * 8]);
    mp[sidx(32 + n2,  lo)] = cmul(a2,  twg[n2 * 4]);
    mp[sidx(96 + n2,  lo)] = cmul(a3,  twg[n2 * 12]);
    mp[sidx(16 + n2,  lo)] = cmul(a4,  twg[n2 * 2]);
    mp[sidx(80 + n2,  lo)] = cmul(a5,  twg[n2 * 10]);
    mp[sidx(48 + n2,  lo)] = cmul(a6,  twg[n2 * 6]);
    mp[sidx(112 + n2, lo)] = cmul(a7,  twg[n2 * 14]);
    mp[sidx(8 + n2,   lo)] = cmul(a8,  twg[n2 * 1]);
    mp[sidx(72 + n2,  lo)] = cmul(a9,  twg[n2 * 9]);
    mp[sidx(40 + n2,  lo)] = cmul(a10, twg[n2 * 5]);
    mp[sidx(104 + n2, lo)] = cmul(a11, twg[n2 * 13]);
    mp[sidx(24 + n2,  lo)] = cmul(a12, twg[n2 * 3]);
    mp[sidx(88 + n2,  lo)] = cmul(a13, twg[n2 * 11]);
    mp[sidx(56 + n2,  lo)] = cmul(a14, twg[n2 * 7]);
    mp[sidx(120 + n2, lo)] = cmul(a15, twg[n2 * 15]);
    __syncthreads();
    // ----- cols stage 2: FFT8 over n2, fold mid twiddle W_M^{r*lo} -----
    {
        float2 b0 = mp[sidx(8 * n2 + 0, lo)];
        float2 b1 = mp[sidx(8 * n2 + 1, lo)];
        float2 b2 = mp[sidx(8 * n2 + 2, lo)];
        float2 b3 = mp[sidx(8 * n2 + 3, lo)];
        float2 b4 = mp[sidx(8 * n2 + 4, lo)];
        float2 b5 = mp[sidx(8 * n2 + 5, lo)];
        float2 b6 = mp[sidx(8 * n2 + 6, lo)];
        float2 b7 = mp[sidx(8 * n2 + 7, lo)];
        float2 c0 = mp[sidx(8 * n2 + 64, lo)];
        float2 c1 = mp[sidx(8 * n2 + 65, lo)];
        float2 c2 = mp[sidx(8 * n2 + 66, lo)];
        float2 c3 = mp[sidx(8 * n2 + 67, lo)];
        float2 c4 = mp[sidx(8 * n2 + 68, lo)];
        float2 c5 = mp[sidx(8 * n2 + 69, lo)];
        float2 c6 = mp[sidx(8 * n2 + 70, lo)];
        float2 c7 = mp[sidx(8 * n2 + 71, lo)];
        __syncthreads();
        fft8s<false>(b0, b1, b2, b3, b4, b5, b6, b7);
        fft8s<false>(c0, c1, c2, c3, c4, c5, c6, c7);
        STW_FWD(b0, n2 + 0);  STW_FWD(b1, n2 + 64);
        STW_FWD(b2, n2 + 32); STW_FWD(b3, n2 + 96);
        STW_FWD(b4, n2 + 16); STW_FWD(b5, n2 + 80);
        STW_FWD(b6, n2 + 48); STW_FWD(b7, n2 + 112);
        STW_FWD(c0, n2 + 8);  STW_FWD(c1, n2 + 72);
        STW_FWD(c2, n2 + 40); STW_FWD(c3, n2 + 104);
        STW_FWD(c4, n2 + 24); STW_FWD(c5, n2 + 88);
        STW_FWD(c6, n2 + 56); STW_FWD(c7, n2 + 120);
    }
    __syncthreads();
    // ----- rows stage 1: FFT16 along lo, twiddle W_128^{n2*k1} -----
    const int hi = lo;
    a0  = mp[sidx(hi, n2)];
    a1  = mp[sidx(hi, 8 + n2)];
    a2  = mp[sidx(hi, 16 + n2)];
    a3  = mp[sidx(hi, 24 + n2)];
    a4  = mp[sidx(hi, 32 + n2)];
    a5  = mp[sidx(hi, 40 + n2)];
    a6  = mp[sidx(hi, 48 + n2)];
    a7  = mp[sidx(hi, 56 + n2)];
    a8  = mp[sidx(hi, 64 + n2)];
    a9  = mp[sidx(hi, 72 + n2)];
    a10 = mp[sidx(hi, 80 + n2)];
    a11 = mp[sidx(hi, 88 + n2)];
    a12 = mp[sidx(hi, 96 + n2)];
    a13 = mp[sidx(hi, 104 + n2)];
    a14 = mp[sidx(hi, 112 + n2)];
    a15 = mp[sidx(hi, 120 + n2)];
    fft16s<false>(a0, a1, a2, a3, a4, a5, a6, a7, a8, a9, a10, a11, a12, a13, a14, a15);
    mp[sidx(hi, n2)]       = a0;
    mp[sidx(hi, 64 + n2)]  = cmul(a1,  twg[n2 * 8]);
    mp[sidx(hi, 32 + n2)]  = cmul(a2,  twg[n2 * 4]);
    mp[sidx(hi, 96 + n2)]  = cmul(a3,  twg[n2 * 12]);
    mp[sidx(hi, 16 + n2)]  = cmul(a4,  twg[n2 * 2]);
    mp[sidx(hi, 80 + n2)]  = cmul(a5,  twg[n2 * 10]);
    mp[sidx(hi, 48 + n2)]  = cmul(a6,  twg[n2 * 6]);
    mp[sidx(hi, 112 + n2)] = cmul(a7,  twg[n2 * 14]);
    mp[sidx(hi, 8 + n2)]   = cmul(a8,  twg[n2 * 1]);
    mp[sidx(hi, 72 + n2)]  = cmul(a9,  twg[n2 * 9]);
    mp[sidx(hi, 40 + n2)]  = cmul(a10, twg[n2 * 5]);
    mp[sidx(hi, 104 + n2)] = cmul(a11, twg[n2 * 13]);
    mp[sidx(hi, 24 + n2)]  = cmul(a12, twg[n2 * 3]);
    mp[sidx(hi, 88 + n2)]  = cmul(a13, twg[n2 * 11]);
    mp[sidx(hi, 56 + n2)]  = cmul(a14, twg[n2 * 7]);
    mp[sidx(hi, 120 + n2)] = cmul(a15, twg[n2 * 15]);
    __syncthreads();
    // ----- rows stage 2: FFT8 over n2 (no extra twiddle) -----
    {
        float2 b0 = mp[sidx(hi, 8 * n2 + 0)];
        float2 b1 = mp[sidx(hi, 8 * n2 + 1)];
        float2 b2 = mp[sidx(hi, 8 * n2 + 2)];
        float2 b3 = mp[sidx(hi, 8 * n2 + 3)];
        float2 b4 = mp[sidx(hi, 8 * n2 + 4)];
        float2 b5 = mp[sidx(hi, 8 * n2 + 5)];
        float2 b6 = mp[sidx(hi, 8 * n2 + 6)];
        float2 b7 = mp[sidx(hi, 8 * n2 + 7)];
        float2 c0 = mp[sidx(hi, 8 * n2 + 64)];
        float2 c1 = mp[sidx(hi, 8 * n2 + 65)];
        float2 c2 = mp[sidx(hi, 8 * n2 + 66)];
        float2 c3 = mp[sidx(hi, 8 * n2 + 67)];
        float2 c4 = mp[sidx(hi, 8 * n2 + 68)];
        float2 c5 = mp[sidx(hi, 8 * n2 + 69)];
        float2 c6 = mp[sidx(hi, 8 * n2 + 70)];
        float2 c7 = mp[sidx(hi, 8 * n2 + 71)];
        __syncthreads();
        fft8s<false>(b0, b1, b2, b3, b4, b5, b6, b7);
        fft8s<false>(c0, c1, c2, c3, c4, c5, c6, c7);
        mp[sidx(hi, n2 + 0)]   = b0;
        mp[sidx(hi, n2 + 64)]  = b1;
        mp[sidx(hi, n2 + 32)]  = b2;
        mp[sidx(hi, n2 + 96)]  = b3;
        mp[sidx(hi, n2 + 16)]  = b4;
        mp[sidx(hi, n2 + 80)]  = b5;
        mp[sidx(hi, n2 + 48)]  = b6;
        mp[sidx(hi, n2 + 112)] = b7;
        mp[sidx(hi, n2 + 8)]   = c0;
        mp[sidx(hi, n2 + 72)]  = c1;
        mp[sidx(hi, n2 + 40)]  = c2;
        mp[sidx(hi, n2 + 104)] = c3;
        mp[sidx(hi, n2 + 24)]  = c4;
        mp[sidx(hi, n2 + 88)]  = c5;
        mp[sidx(hi, n2 + 56)]  = c6;
        mp[sidx(hi, n2 + 120)] = c7;
    }
    __syncthreads();
}

// ---------------------------------------------------------------------------
// K0: per-bin scan of G for nonzero head/tail block sizes (exact-0 padding).
// ---------------------------------------------------------------------------
__global__ void k0_scan(const float* __restrict__ G, int NL, int* __restrict__ hnh) {
    const int j = blockIdx.x;
    __shared__ int s_first, s_last;
    if (threadIdx.x == 0) { s_first = NL; s_last = -1; }
    __syncthreads();
    const float* Gj = G + (size_t)j * NL;
    for (int m = threadIdx.x; m < NL; m += blockDim.x) {
        if (Gj[m] == 0.0f) {
            atomicMin(&s_first, m);
            atomicMax(&s_last, m);
        }
    }
    __syncthreads();
    if (threadIdx.x == 0) {
        int h  = s_first;
        int nh = (s_last >= 0) ? (NL - 1 - s_last) : 0;
        hnh[2 * j]     = h;
        hnh[2 * j + 1] = nh;
    }
}

// ---------------------------------------------------------------------------
// K1: 525-point DFT per (n2, r), split 525 = 25 x 21 (Cooley-Tukey in LDS).
// ---------------------------------------------------------------------------
__global__ __launch_bounds__(TPB) void k1_dft525(const float* __restrict__ x,
                                                 float2* __restrict__ A) {
    const int n2 = blockIdx.x;
    const int r  = blockIdx.y;
    __shared__ float  xs[N1];
    __shared__ float2 ys[N1];
    __shared__ float2 w25[25];
    __shared__ float2 w21[21];
    const float* xr = x + (size_t)r * LS + n2;
    for (int t = threadIdx.x; t < N1; t += TPB) {
        xs[t] = xr[(size_t)t * N2];
    }
    if (threadIdx.x < 25) {
        float a = -TWO_PI_F * (float)threadIdx.x / 25.0f;
        float s, c; sincosf(a, &s, &c);
        w25[threadIdx.x] = make_float2(c, s);
    } else if (threadIdx.x >= 32 && threadIdx.x < 53) {
        int k = threadIdx.x - 32;
        float a = -TWO_PI_F * (float)k / 21.0f;
        float s, c; sincosf(a, &s, &c);
        w21[k] = make_float2(c, s);
    }
    __syncthreads();
    for (int i = threadIdx.x; i < N1; i += TPB) {
        int alpha = i % 25, b = i / 25;
        float re = 0.f, im = 0.f;
        int iw = 0, it = b;
        #pragma unroll
        for (int a = 0; a < 25; ++a) {
            float  v = xs[it];
            float2 w = w25[iw];
            re = fmaf(v, w.x, re);
            im = fmaf(v, w.y, im);
            it += 21;
            iw += alpha; if (iw >= 25) iw -= 25;
        }
        float ang = -TWO_PI_F * (float)(b * alpha) / (float)N1;
        float s, c; sincosf(ang, &s, &c);
        ys[i] = make_float2(re * c - im * s, re * s + im * c);
    }
    __syncthreads();
    for (int k = threadIdx.x; k < N1; k += TPB) {
        int alpha = k % 25, beta = k / 25;
        float re = 0.f, im = 0.f;
        int iw = 0, iy = alpha;
        #pragma unroll
        for (int b = 0; b < 21; ++b) {
            float2 v = ys[iy];
            float2 w = w21[iw];
            re = fmaf(v.x, w.x, re); re = fmaf(-v.y, w.y, re);
            im = fmaf(v.x, w.y, im); im = fmaf( v.y, w.x, im);
            iy += 25;
            iw += beta; if (iw >= 21) iw -= 21;
        }
        float ang = -TWO_PI_F * (float)(k * n2) / (float)LS;
        float s, c; sincosf(ang, &s, &c);
        A[((size_t)r * N1 + k) * N2 + n2] = make_float2(re * c - im * s, re * s + im * c);
    }
}

// ---------------------------------------------------------------------------
// K2: 504-point DFT per (k1, r), split 504 = 21 x 24 (Cooley-Tukey in LDS).
// ---------------------------------------------------------------------------
__global__ __launch_bounds__(TPB) void k2_dft504(float2* __restrict__ A) {
    const int k1 = blockIdx.x;
    const int r  = blockIdx.y;
    __shared__ float2 as[N2];
    __shared__ float2 ys[N2];
    __shared__ float2 w21[21];
    __shared__ float2 w24[24];
    float2* row = A + ((size_t)r * N1 + k1) * N2;
    for (int t = threadIdx.x; t < N2; t += TPB) as[t] = row[t];
    if (threadIdx.x < 21) {
        float a = -TWO_PI_F * (float)threadIdx.x / 21.0f;
        float s, c; sincosf(a, &s, &c);
        w21[threadIdx.x] = make_float2(c, s);
    } else if (threadIdx.x >= 32 && threadIdx.x < 56) {
        int k = threadIdx.x - 32;
        float a = -TWO_PI_F * (float)k / 24.0f;
        float s, c; sincosf(a, &s, &c);
        w24[k] = make_float2(c, s);
    }
    __syncthreads();
    for (int i = threadIdx.x; i < N2; i += TPB) {
        int alpha = i % 21, b = i / 21;
        float re = 0.f, im = 0.f;
        int iw = 0, it = b;
        #pragma unroll
        for (int a = 0; a < 21; ++a) {
            float2 v = as[it];
            float2 w = w21[iw];
            re = fmaf(v.x, w.x, re); re = fmaf(-v.y, w.y, re);
            im = fmaf(v.x, w.y, im); im = fmaf( v.y, w.x, im);
            it += 24;
            iw += alpha; if (iw >= 21) iw -= 21;
        }
        float ang = -TWO_PI_F * (float)(b * alpha) / (float)N2;
        float s, c; sincosf(ang, &s, &c);
        ys[i] = make_float2(re * c - im * s, re * s + im * c);
    }
    __syncthreads();
    for (int k = threadIdx.x; k < N2; k += TPB) {
        int alpha = k % 21, beta = k / 21;
        float re = 0.f, im = 0.f;
        int iw = 0, iy = alpha;
        #pragma unroll
        for (int b = 0; b < 24; ++b) {
            float2 v = ys[iy];
            float2 w = w24[iw];
            re = fmaf(v.x, w.x, re); re = fmaf(-v.y, w.y, re);
            im = fmaf(v.x, w.y, im); im = fmaf( v.y, w.x, im);
            iy += 21;
            iw += beta; if (iw >= 24) iw -= 24;
        }
        row[k] = make_float2(re, im);
    }
}

// ---------------------------------------------------------------------------
// K_SETUP: chirp tables + W_128 table + 16K-entry W_M table.
// ---------------------------------------------------------------------------
__global__ void k_setup(float2* __restrict__ kc, float2* __restrict__ bchirp,
                        float2* __restrict__ twg, float2* __restrict__ twM, int NL) {
    int t = blockIdx.x * blockDim.x + threadIdx.x;
    long long twoNL = 2LL * NL;
    if (t < M_FFT) {
        long long d = 0; bool act = false;
        if (t < NL)              { d = t;        act = true; }
        else if (t > M_FFT - NL) { d = t - M_FFT; act = true; }
        float2 v = make_float2(0.f, 0.f);
        if (act) {
            long long ph = (d * d) % twoNL;
            float th = -PI_F * (float)ph / (float)NL;
            float s, c; sincosf(th, &s, &c);
            v = make_float2(c, s);
        }
        kc[t] = v;
    } else {
        int n = t - M_FFT;
        if (n < NL) {
            long long ph = ((long long)n * n) % twoNL;
            float th = PI_F * (float)ph / (float)NL;
            float s, c; sincosf(th, &s, &c);
            bchirp[n] = make_float2(c, s);
        } else if (n < NL + 128) {
            int q = n - NL;
            float th = -TWO_PI_F * (float)q / 128.0f;
            float s, c; sincosf(th, &s, &c);
            twg[q] = make_float2(c, s);
        } else if (n < NL + 128 + M_FFT) {
            int q = n - NL - 128;
            float th = -TWO_PI_F * (float)q / (float)M_FFT;
            float s, c; sincosf(th, &s, &c);
            twM[q] = make_float2(c, s);
        }
    }
}

// ---------------------------------------------------------------------------
// K_KF: one block. KFt[s*128 + r] = FFT16k(kc)[r + 128*s]  (transposed store
// so k_fused's inverse-row loads are coalesced).
// ---------------------------------------------------------------------------
__global__ __launch_bounds__(TPF, 4)
void k_kf(const float2* __restrict__ kc, const float2* __restrict__ twg,
          const float2* __restrict__ twM, float2* __restrict__ KFt) {
    extern __shared__ float2 mp[];
    const int tid = threadIdx.x;
    const int lo = tid & 127, n2 = tid >> 7;
    for (int i = tid; i < M_FFT; i += TPF)
        mp[sidx(i >> 7, i & 127)] = kc[i];
    fwd_core(mp, twg, twM, lo, n2);
    for (int i = tid; i < M_FFT; i += TPF) {
        int hh = i >> 7, ll = i & 127;
        KFt[(size_t)ll * 128 + hh] = mp[sidx(hh, ll)];
    }
}

// ---------------------------------------------------------------------------
// K_FUSED: one transform per block; gather -> fwd -> xKF -> inv -> out.
// Gather is a low-pressure strided loop into LDS (round-2 pattern); FFT
// stages use named scalar registers. __launch_bounds__(1024,4): 4 waves/EU
// min = 1 block/CU (already LDS-imposed) -> 128-VGPR budget, no spill.
// ---------------------------------------------------------------------------
#define FINST(var, acol) do {                                                 \
    const int n_ = 128 * (acol) + lo;                                         \
    if (n_ < NL) {                                                            \
        float2 y_ = cmul((var), bchirp[n_]);                                  \
        outv[n_] = make_float2(y_.x * sc, y_.y * sc);                         \
    }                                                                         \
} while (0)

__global__ __launch_bounds__(TPF, 4)
void k_fused(const float* __restrict__ Gm,
        const int* __restrict__ idxp, const float2* __restrict__ A,
        const int* __restrict__ hnh, const float2* __restrict__ bchirp,
        const float2* __restrict__ KFt, const float2* __restrict__ twg,
        const float2* __restrict__ twM,
        float2* __restrict__ out, int NB, int NL) {
    extern __shared__ float2 mp[];
    const int tid = threadIdx.x;
    const int lo = tid & 127, n2 = tid >> 7;
    const int vg = blockIdx.x;
    const int rr_ = vg / NB, jb = vg % NB;
    const int h = hnh[2 * jb], nh = hnh[2 * jb + 1];
    const int tail0 = NL - nh;
    const float* Gj = Gm + (size_t)jb * NL;
    const int*   ij = idxp + (size_t)jb * NL;
    const float2* Ar = A + (size_t)rr_ * LS;

    // ===== gather into LDS natural layout (<=3 live values, no spill) =====
    for (int i = tid; i < M_FFT; i += TPF) {
        float2 val = make_float2(0.f, 0.f);
        if (i < h || (i >= tail0 && i < NL)) {
            int k = ij[i];
            float2 f = Ar[(size_t)(k % N1) * N2 + (k / N1)];
            float  g = Gj[i];
            val = cmul(make_float2(f.x * g, f.y * g), bchirp[i]);
        }
        mp[sidx(i >> 7, i & 127)] = val;
    }
    fwd_core(mp, twg, twM, lo, n2);
    // mp(r, s) = X[r + 128*s]

    const int hi = lo;
    // ===== inverse rows stage 1: xKF^T at load, IFFT16, conj twiddle =====
    float2 a0  = cmul(mp[sidx(hi, n2)],       KFt[(size_t)(n2) * 128 + hi]);
    float2 a1  = cmul(mp[sidx(hi, 8 + n2)],   KFt[(size_t)(8 + n2) * 128 + hi]);
    float2 a2  = cmul(mp[sidx(hi, 16 + n2)],  KFt[(size_t)(16 + n2) * 128 + hi]);
    float2 a3  = cmul(mp[sidx(hi, 24 + n2)],  KFt[(size_t)(24 + n2) * 128 + hi]);
    float2 a4  = cmul(mp[sidx(hi, 32 + n2)],  KFt[(size_t)(32 + n2) * 128 + hi]);
    float2 a5  = cmul(mp[sidx(hi, 40 + n2)],  KFt[(size_t)(40 + n2) * 128 + hi]);
    float2 a6  = cmul(mp[sidx(hi, 48 + n2)],  KFt[(size_t)(48 + n2) * 128 + hi]);
    float2 a7  = cmul(mp[sidx(hi, 56 + n2)],  KFt[(size_t)(56 + n2) * 128 + hi]);
    float2 a8  = cmul(mp[sidx(hi, 64 + n2)],  KFt[(size_t)(64 + n2) * 128 + hi]);
    float2 a9  = cmul(mp[sidx(hi, 72 + n2)],  KFt[(size_t)(72 + n2) * 128 + hi]);
    float2 a10 = cmul(mp[sidx(hi, 80 + n2)],  KFt[(size_t)(80 + n2) * 128 + hi]);
    float2 a11 = cmul(mp[sidx(hi, 88 + n2)],  KFt[(size_t)(88 + n2) * 128 + hi]);
    float2 a12 = cmul(mp[sidx(hi, 96 + n2)],  KFt[(size_t)(96 + n2) * 128 + hi]);
    float2 a13 = cmul(mp[sidx(hi, 104 + n2)], KFt[(size_t)(104 + n2) * 128 + hi]);
    float2 a14 = cmul(mp[sidx(hi, 112 + n2)], KFt[(size_t)(112 + n2) * 128 + hi]);
    float2 a15 = cmul(mp[sidx(hi, 120 + n2)], KFt[(size_t)(120 + n2) * 128 + hi]);
    fft16s<true>(a0, a1, a2, a3, a4, a5, a6, a7, a8, a9, a10, a11, a12, a13, a14, a15);
    mp[sidx(hi, n2)]       = a0;
    mp[sidx(hi, 64 + n2)]  = cmul(a1,  CTW(twg[n2 * 8]));
    mp[sidx(hi, 32 + n2)]  = cmul(a2,  CTW(twg[n2 * 4]));
    mp[sidx(hi, 96 + n2)]  = cmul(a3,  CTW(twg[n2 * 12]));
    mp[sidx(hi, 16 + n2)]  = cmul(a4,  CTW(twg[n2 * 2]));
    mp[sidx(hi, 80 + n2)]  = cmul(a5,  CTW(twg[n2 * 10]));
    mp[sidx(hi, 48 + n2)]  = cmul(a6,  CTW(twg[n2 * 6]));
    mp[sidx(hi, 112 + n2)] = cmul(a7,  CTW(twg[n2 * 14]));
    mp[sidx(hi, 8 + n2)]   = cmul(a8,  CTW(twg[n2 * 1]));
    mp[sidx(hi, 72 + n2)]  = cmul(a9,  CTW(twg[n2 * 9]));
    mp[sidx(hi, 40 + n2)]  = cmul(a10, CTW(twg[n2 * 5]));
    mp[sidx(hi, 104 + n2)] = cmul(a11, CTW(twg[n2 * 13]));
    mp[sidx(hi, 24 + n2)]  = cmul(a12, CTW(twg[n2 * 3]));
    mp[sidx(hi, 88 + n2)]  = cmul(a13, CTW(twg[n2 * 11]));
    mp[sidx(hi, 56 + n2)]  = cmul(a14, CTW(twg[n2 * 7]));
    mp[sidx(hi, 120 + n2)] = cmul(a15, CTW(twg[n2 * 15]));
    __syncthreads();
    // ===== inverse rows stage 2: IFFT8, fold inv mid twiddle =====
    {
        float2 b0 = mp[sidx(hi, 8 * n2 + 0)];
        float2 b1 = mp[sidx(hi, 8 * n2 + 1)];
        float2 b2 = mp[sidx(hi, 8 * n2 + 2)];
        float2 b3 = mp[sidx(hi, 8 * n2 + 3)];
        float2 b4 = mp[sidx(hi, 8 * n2 + 4)];
        float2 b5 = mp[sidx(hi, 8 * n2 + 5)];
        float2 b6 = mp[sidx(hi, 8 * n2 + 6)];
        float2 b7 = mp[sidx(hi, 8 * n2 + 7)];
        float2 c0 = mp[sidx(hi, 8 * n2 + 64)];
        float2 c1 = mp[sidx(hi, 8 * n2 + 65)];
        float2 c2 = mp[sidx(hi, 8 * n2 + 66)];
        float2 c3 = mp[sidx(hi, 8 * n2 + 67)];
        float2 c4 = mp[sidx(hi, 8 * n2 + 68)];
        float2 c5 = mp[sidx(hi, 8 * n2 + 69)];
        float2 c6 = mp[sidx(hi, 8 * n2 + 70)];
        float2 c7 = mp[sidx(hi, 8 * n2 + 71)];
        __syncthreads();
        fft8s<true>(b0, b1, b2, b3, b4, b5, b6, b7);
        fft8s<true>(c0, c1, c2, c3, c4, c5, c6, c7);
        STW_INV(b0, n2 + 0);  STW_INV(b1, n2 + 64);
        STW_INV(b2, n2 + 32); STW_INV(b3, n2 + 96);
        STW_INV(b4, n2 + 16); STW_INV(b5, n2 + 80);
        STW_INV(b6, n2 + 48); STW_INV(b7, n2 + 112);
        STW_INV(c0, n2 + 8);  STW_INV(c1, n2 + 72);
        STW_INV(c2, n2 + 40); STW_INV(c3, n2 + 104);
        STW_INV(c4, n2 + 24); STW_INV(c5, n2 + 88);
        STW_INV(c6, n2 + 56); STW_INV(c7, n2 + 120);
    }
    __syncthreads();
    // ===== inverse cols stage 1: IFFT16 over hi, conj twiddle =====
    a0  = mp[sidx(n2, lo)];
    a1  = mp[sidx(8 + n2, lo)];
    a2  = mp[sidx(16 + n2, lo)];
    a3  = mp[sidx(24 + n2, lo)];
    a4  = mp[sidx(32 + n2, lo)];
    a5  = mp[sidx(40 + n2, lo)];
    a6  = mp[sidx(48 + n2, lo)];
    a7  = mp[sidx(56 + n2, lo)];
    a8  = mp[sidx(64 + n2, lo)];
    a9  = mp[sidx(72 + n2, lo)];
    a10 = mp[sidx(80 + n2, lo)];
    a11 = mp[sidx(88 + n2, lo)];
    a12 = mp[sidx(96 + n2, lo)];
    a13 = mp[sidx(104 + n2, lo)];
    a14 = mp[sidx(112 + n2, lo)];
    a15 = mp[sidx(120 + n2, lo)];
    fft16s<true>(a0, a1, a2, a3, a4, a5, a6, a7, a8, a9, a10, a11, a12, a13, a14, a15);
    mp[sidx(n2, lo)]       = a0;
    mp[sidx(64 + n2, lo)]  = cmul(a1,  CTW(twg[n2 * 8]));
    mp[sidx(32 + n2, lo)]  = cmul(a2,  CTW(twg[n2 * 4]));
    mp[sidx(96 + n2, lo)]  = cmul(a3,  CTW(twg[n2 * 12]));
    mp[sidx(16 + n2, lo)]  = cmul(a4,  CTW(twg[n2 * 2]));
    mp[sidx(80 + n2, lo)]  = cmul(a5,  CTW(twg[n2 * 10]));
    mp[sidx(48 + n2, lo)]  = cmul(a6,  CTW(twg[n2 * 6]));
    mp[sidx(112 + n2, lo)] = cmul(a7,  CTW(twg[n2 * 14]));
    mp[sidx(8 + n2, lo)]   = cmul(a8,  CTW(twg[n2 * 1]));
    mp[sidx(72 + n2, lo)]  = cmul(a9,  CTW(twg[n2 * 9]));
    mp[sidx(40 + n2, lo)]  = cmul(a10, CTW(twg[n2 * 5]));
    mp[sidx(104 + n2, lo)] = cmul(a11, CTW(twg[n2 * 13]));
    mp[sidx(24 + n2, lo)]  = cmul(a12, CTW(twg[n2 * 3]));
    mp[sidx(88 + n2, lo)]  = cmul(a13, CTW(twg[n2 * 11]));
    mp[sidx(56 + n2, lo)]  = cmul(a14, CTW(twg[n2 * 7]));
    mp[sidx(120 + n2, lo)] = cmul(a15, CTW(twg[n2 * 15]));
    __syncthreads();
    // ===== inverse cols stage 2: IFFT8 -> y[128*a + lo] -> global out =====
    {
        float2 b0 = mp[sidx(8 * n2 + 0, lo)];
        float2 b1 = mp[sidx(8 * n2 + 1, lo)];
        float2 b2 = mp[sidx(8 * n2 + 2, lo)];
        float2 b3 = mp[sidx(8 * n2 + 3, lo)];
        float2 b4 = mp[sidx(8 * n2 + 4, lo)];
        float2 b5 = mp[sidx(8 * n2 + 5, lo)];
        float2 b6 = mp[sidx(8 * n2 + 6, lo)];
        float2 b7 = mp[sidx(8 * n2 + 7, lo)];
        float2 c0 = mp[sidx(8 * n2 + 64, lo)];
        float2 c1 = mp[sidx(8 * n2 + 65, lo)];
        float2 c2 = mp[sidx(8 * n2 + 66, lo)];
        float2 c3 = mp[sidx(8 * n2 + 67, lo)];
        float2 c4 = mp[sidx(8 * n2 + 68, lo)];
        float2 c5 = mp[sidx(8 * n2 + 69, lo)];
        float2 c6 = mp[sidx(8 * n2 + 70, lo)];
        float2 c7 = mp[sidx(8 * n2 + 71, lo)];
        fft8s<true>(b0, b1, b2, b3, b4, b5, b6, b7);
        fft8s<true>(c0, c1, c2, c3, c4, c5, c6, c7);
        const float sc = 100.0f / ((float)NL * (float)M_FFT);
        float2* outv = out + (size_t)vg * NL;
        FINST(b0, n2 + 0);  FINST(b1, n2 + 64);
        FINST(b2, n2 + 32); FINST(b3, n2 + 96);
        FINST(b4, n2 + 16); FINST(b5, n2 + 80);
        FINST(b6, n2 + 48); FINST(b7, n2 + 112);
        FINST(c0, n2 + 8);  FINST(c1, n2 + 72);
        FINST(c2, n2 + 40); FINST(c3, n2 + 104);
        FINST(c4, n2 + 24); FINST(c5, n2 + 88);
        FINST(c6, n2 + 56); FINST(c7, n2 + 120);
    }
}

// ---------------------------------------------------------------------------
// Legacy direct zoom-IDFT — fallback if NL too large or ws too small.
// ---------------------------------------------------------------------------
__global__ __launch_bounds__(TPB) void k3_idft(const float* __restrict__ G,
                                               const int*  __restrict__ idxp,
                                               const float2* __restrict__ FT,
                                               const int*  __restrict__ hnh,
                                               float2* __restrict__ out,
                                               int NB, int NL) {
    extern __shared__ float2 cls[];
    const int j = blockIdx.x;
    const int r = blockIdx.y;
    const int h  = hnh[2 * j];
    const int nh = hnh[2 * j + 1];
    const int Lg = h + nh;
    const float* Gj = G    + (size_t)j * NL;
    const int*   ij = idxp + (size_t)j * NL;

    for (int t = threadIdx.x; t < Lg; t += TPB) {
        int m = (t < h) ? t : (NL - nh + (t - h));
        int k = ij[m];
        float2 f = FT[((size_t)r * N1 + (k % N1)) * N2 + (k / N1)];
        float  g = Gj[m];
        cls[t] = make_float2(f.x * g, f.y * g);
    }
    __syncthreads();

    const float scale = 100.0f / (float)NL;
    const float w0 = TWO_PI_F / (float)NL;
    float2* outr = out + ((size_t)r * NB + j) * NL;

    for (int n_base = 0; n_base < NL; n_base += 4 * TPB) {
        int   n[4];
        float are[4], aim[4], twr[4], twi[4], str[4], sti[4];
        #pragma unroll
        for (int u = 0; u < 4; ++u) {
            n[u] = n_base + u * TPB + (int)threadIdx.x;
            are[u] = 0.f; aim[u] = 0.f;
            float s, c; sincosf(w0 * (float)(n[u] % NL), &s, &c);
            str[u] = c; sti[u] = s;
            twr[u] = 1.f; twi[u] = 0.f;
        }
        for (int t = 0; t < h; ++t) {
            if ((t & 255) == 0) {
                #pragma unroll
                for (int u = 0; u < 4; ++u) {
                    int mm = (int)(((long long)t * (long long)n[u]) % NL);
                    float s, c; sincosf(w0 * (float)mm, &s, &c);
                    twr[u] = c; twi[u] = s;
                }
            }
            float2 cv = cls[t];
            #pragma unroll
            for (int u = 0; u < 4; ++u) {
                are[u] = fmaf(cv.x, twr[u], are[u]);
                are[u] = fmaf(-cv.y, twi[u], are[u]);
                aim[u] = fmaf(cv.x, twi[u], aim[u]);
                aim[u] = fmaf(cv.y, twr[u], aim[u]);
                float nr = twr[u] * str[u] - twi[u] * sti[u];
                float ni = twr[u] * sti[u] + twi[u] * str[u];
                twr[u] = nr; twi[u] = ni;
            }
        }
        const int m0 = NL - nh;
        for (int t = 0; t < nh; ++t) {
            if ((t & 255) == 0) {
                #pragma unroll
                for (int u = 0; u < 4; ++u) {
                    int mm = (int)(((long long)(m0 + t) * (long long)n[u]) % NL);
                    float s, c; sincosf(w0 * (float)mm, &s, &c);
                    twr[u] = c; twi[u] = s;
                }
            }
            float2 cv = cls[h + t];
            #pragma unroll
            for (int u = 0; u < 4; ++u) {
                are[u] = fmaf(cv.x, twr[u], are[u]);
                are[u] = fmaf(-cv.y, twi[u], are[u]);
                aim[u] = fmaf(cv.x, twi[u], aim[u]);
                aim[u] = fmaf(cv.y, twr[u], aim[u]);
                float nr = twr[u] * str[u] - twi[u] * sti[u];
                float ni = twr[u] * sti[u] + twi[u] * str[u];
                twr[u] = nr; twi[u] = ni;
            }
        }
        #pragma unroll
        for (int u = 0; u < 4; ++u) {
            if (n[u] < NL) outr[n[u]] = make_float2(are[u] * scale, aim[u] * scale);
        }
    }
}

// ---------------------------------------------------------------------------
static inline size_t align256(size_t x) { return (x + 255) & ~(size_t)255; }

extern "C" void kernel_launch(void* const* d_in, const int* in_sizes, int n_in,
                              void* d_out, int out_size, void* d_ws, size_t ws_size,
                              hipStream_t stream) {
    const float* x   = (const float*)d_in[0];
    const float* Gm  = (const float*)d_in[1];
    const int*   idx = (const int*)d_in[2];
    float2*      out = (float2*)d_out;

    const int p  = in_sizes[1];
    const int NB = (p % 114 == 0) ? 114 : 115;
    const int NL = p / NB;
    const int B  = NB * ROWS;

    // ws layout: hnh | bchirp | twg(128) | twM(16384) | kc | KFt | A
    size_t hnh_off    = 0;
    size_t bchirp_off = align256(hnh_off + 2048);
    size_t twg_off    = align256(bchirp_off + (size_t)NL * 8);
    size_t twM_off    = align256(twg_off + 128 * 8);
    size_t kc_off     = align256(twM_off + (size_t)M_FFT * 8);
    size_t kft_off    = align256(kc_off + (size_t)M_FFT * 8);
    size_t A_off      = align256(kft_off + (size_t)M_FFT * 8);
    size_t need       = A_off + (size_t)ROWS * LS * 8;

    int*    hnh    = (int*)((char*)d_ws + hnh_off);
    float2* bchirp = (float2*)((char*)d_ws + bchirp_off);
    float2* twg    = (float2*)((char*)d_ws + twg_off);
    float2* twM    = (float2*)((char*)d_ws + twM_off);
    float2* kc     = (float2*)((char*)d_ws + kc_off);
    float2* KFt    = (float2*)((char*)d_ws + kft_off);
    float2* A      = (float2*)((char*)d_ws + A_off);

    k0_scan<<<dim3(NB), TPB, 0, stream>>>(Gm, NL, hnh);
    k1_dft525<<<dim3(N2, ROWS), TPB, 0, stream>>>(x, A);
    k2_dft504<<<dim3(N1, ROWS), TPB, 0, stream>>>(A);

    const bool fused_ok = (2 * NL - 1 <= M_FFT) && (need <= ws_size);
    if (fused_ok) {
        (void)hipFuncSetAttribute((const void*)k_fused,
                                  hipFuncAttributeMaxDynamicSharedMemorySize,
                                  M_FFT * (int)sizeof(float2));
        (void)hipFuncSetAttribute((const void*)k_kf,
                                  hipFuncAttributeMaxDynamicSharedMemorySize,
                                  M_FFT * (int)sizeof(float2));
        int setup_blocks = (2 * M_FFT + NL + 128 + TPB - 1) / TPB;
        k_setup<<<dim3(setup_blocks), TPB, 0, stream>>>(kc, bchirp, twg, twM, NL);
        k_kf<<<dim3(1), TPF, (size_t)M_FFT * sizeof(float2), stream>>>(kc, twg, twM, KFt);
        k_fused<<<dim3(B), TPF, (size_t)M_FFT * sizeof(float2), stream>>>(
            Gm, idx, A, hnh, bchirp, KFt, twg, twM, out, NB, NL);
    } else {
        k3_idft<<<dim3(NB, ROWS), TPB, (size_t)NL * sizeof(float2), stream>>>(
            Gm, idx, A, hnh, out, NB, NL);
    }
}

// Round 7
// 1315.307 us; speedup vs baseline: 1.3211x; 1.3191x over previous
//
#include <hip/hip_runtime.h>

#define TPB 256
#define TPF 1024
constexpr int LS = 264600;          // 6.0 s * 44100 Hz
constexpr int N1 = 525;             // LS = N1 * N2
constexpr int N2 = 504;
constexpr int ROWS = 32;            // S*C = 16*2
constexpr int M_FFT = 16384;        // Bluestein conv length >= 2*NL-1 (NL<=8192)
constexpr float TWO_PI_F = 6.28318530717958647692f;
constexpr float PI_F     = 3.14159265358979323846f;

__device__ __forceinline__ int rev7(int x) { return (int)(__brev((unsigned)x) >> 25); }
__device__ __forceinline__ float2 cmul(float2 a, float2 b) {
    return make_float2(a.x * b.x - a.y * b.y, a.x * b.y + a.y * b.x);
}
__device__ __forceinline__ float2 cmulc(float2 a, float2 w) {   // a * conj(w)
    return make_float2(a.x * w.x + a.y * w.y, a.y * w.x - a.x * w.y);
}
__device__ __forceinline__ float2 cadd(float2 a, float2 b) { return make_float2(a.x + b.x, a.y + b.y); }
__device__ __forceinline__ float2 csub(float2 a, float2 b) { return make_float2(a.x - b.x, a.y - b.y); }
// XOR-swizzled LDS index for the 128x128 array (round-2 proven).
__device__ __forceinline__ int sidx(int hi, int lo) {
    return (hi << 7) + (lo ^ (hi & 15));
}
// OVER_HI: FFT runs along the hi coordinate (col FFTs); else along lo (rows).
template<bool OVER_HI>
__device__ __forceinline__ int midx(int p, int f) {
    return OVER_HI ? sidx(p, f) : sidx(f, p);
}

// ---------------------------------------------------------------------------
// Fused radix-2 stage-pair (DIF: spans S, S/2; in-place on quad
// {u, u+S2, u+S, u+S+S2}).  Exactly two cascade stages -> layout unchanged.
// ---------------------------------------------------------------------------
__device__ __forceinline__ void dif_pair(float2 &v0, float2 &v1, float2 &v2, float2 &v3,
                                         float2 wA0, float2 wA1, float2 wB) {
    float2 s0 = cadd(v0, v2), d0 = cmul(csub(v0, v2), wA0);
    float2 s1 = cadd(v1, v3), d1 = cmul(csub(v1, v3), wA1);
    v0 = cadd(s0, s1); v1 = cmul(csub(s0, s1), wB);
    v2 = cadd(d0, d1); v3 = cmul(csub(d0, d1), wB);
}
// DIT pair (spans S/2 then S), conj twiddles; in-place on the same quad.
__device__ __forceinline__ void dit_pair(float2 &v0, float2 &v1, float2 &v2, float2 &v3,
                                         float2 wA, float2 wB0, float2 wB1) {
    float2 t  = cmulc(v1, wA);
    float2 a0 = cadd(v0, t), a1 = csub(v0, t);
    float2 t2 = cmulc(v3, wA);
    float2 b0 = cadd(v2, t2), b1 = csub(v2, t2);
    t  = cmulc(b0, wB0); v0 = cadd(a0, t);  v2 = csub(a0, t);
    t2 = cmulc(b1, wB1); v1 = cadd(a1, t2); v3 = csub(a1, t2);
}

// In-place DIF FFT-8 on 8 contiguous cascade slots (stages span 4,2,1).
#define BFLY(u, w, C, S) do {                       \
    float dx_ = (u).x - (w).x, dy_ = (u).y - (w).y; \
    (u).x += (w).x; (u).y += (w).y;                 \
    (w).x = dx_ * (C) - dy_ * (S);                  \
    (w).y = dx_ * (S) + dy_ * (C);                  \
} while (0)
__device__ __forceinline__ void dif8(float2 &b0, float2 &b1, float2 &b2, float2 &b3,
                                     float2 &b4, float2 &b5, float2 &b6, float2 &b7) {
    constexpr float r2 = 0.70710678118654752f;
    BFLY(b0, b4, 1.f, 0.f);
    BFLY(b1, b5, r2, -r2);
    BFLY(b2, b6, 0.f, -1.f);
    BFLY(b3, b7, -r2, -r2);
    BFLY(b0, b2, 1.f, 0.f);
    BFLY(b1, b3, 0.f, -1.f);
    BFLY(b4, b6, 1.f, 0.f);
    BFLY(b5, b7, 0.f, -1.f);
    BFLY(b0, b1, 1.f, 0.f);
    BFLY(b2, b3, 1.f, 0.f);
    BFLY(b4, b5, 1.f, 0.f);
    BFLY(b6, b7, 1.f, 0.f);
}
// In-place DIT IFFT-8 (stages span 1,2,4, conj twiddles).
#define DITB(u, w, C, S) do {                                        \
    float2 t_ = make_float2((w).x * (C) - (w).y * (S),               \
                            (w).x * (S) + (w).y * (C));              \
    (w) = csub((u), t_); (u) = cadd((u), t_);                        \
} while (0)
__device__ __forceinline__ void dit8(float2 &b0, float2 &b1, float2 &b2, float2 &b3,
                                     float2 &b4, float2 &b5, float2 &b6, float2 &b7) {
    constexpr float r2 = 0.70710678118654752f;
    DITB(b0, b1, 1.f, 0.f);
    DITB(b2, b3, 1.f, 0.f);
    DITB(b4, b5, 1.f, 0.f);
    DITB(b6, b7, 1.f, 0.f);
    DITB(b0, b2, 1.f, 0.f);
    DITB(b1, b3, 0.f, 1.f);
    DITB(b4, b6, 1.f, 0.f);
    DITB(b5, b7, 0.f, 1.f);
    DITB(b0, b4, 1.f, 0.f);
    DITB(b1, b5, r2, r2);
    DITB(b2, b6, 0.f, 1.f);
    DITB(b3, b7, -r2, r2);
}

// ---------------------------------------------------------------------------
// Generic sweeps (no folds). 4096 quads / 2048 octs per sweep, tid-strided.
// ---------------------------------------------------------------------------
template<bool OVER_HI>
__device__ __forceinline__ void sweep_pair6_dif(float2* mp, const float2* tws, int tid) {
    #pragma unroll
    for (int it = 0; it < 4; ++it) {
        int qq = tid + (it << 10);
        int f = qq & 127, j = qq >> 7;                 // j in [0,32), u = j
        float2 v0 = mp[midx<OVER_HI>(j,      f)];
        float2 v1 = mp[midx<OVER_HI>(j + 32, f)];
        float2 v2 = mp[midx<OVER_HI>(j + 64, f)];
        float2 v3 = mp[midx<OVER_HI>(j + 96, f)];
        dif_pair(v0, v1, v2, v3, tws[j], tws[j + 32], tws[j << 1]);
        mp[midx<OVER_HI>(j,      f)] = v0;
        mp[midx<OVER_HI>(j + 32, f)] = v1;
        mp[midx<OVER_HI>(j + 64, f)] = v2;
        mp[midx<OVER_HI>(j + 96, f)] = v3;
    }
}
template<bool OVER_HI>
__device__ __forceinline__ void sweep_pair4_dif(float2* mp, const float2* tws, int tid) {
    #pragma unroll
    for (int it = 0; it < 4; ++it) {
        int qq = tid + (it << 10);
        int f = qq & 127, b = qq >> 7;
        int j = b & 7, g = b >> 3, u = (g << 5) + j;
        float2 v0 = mp[midx<OVER_HI>(u,      f)];
        float2 v1 = mp[midx<OVER_HI>(u + 8,  f)];
        float2 v2 = mp[midx<OVER_HI>(u + 16, f)];
        float2 v3 = mp[midx<OVER_HI>(u + 24, f)];
        dif_pair(v0, v1, v2, v3, tws[j << 2], tws[(j + 8) << 2], tws[j << 3]);
        mp[midx<OVER_HI>(u,      f)] = v0;
        mp[midx<OVER_HI>(u + 8,  f)] = v1;
        mp[midx<OVER_HI>(u + 16, f)] = v2;
        mp[midx<OVER_HI>(u + 24, f)] = v3;
    }
}
template<bool OVER_HI>
__device__ __forceinline__ void sweep_oct_dif(float2* mp, int tid) {
    #pragma unroll
    for (int it = 0; it < 2; ++it) {
        int qq = tid + (it << 10);
        int f = qq & 127, u = (qq >> 7) << 3;
        float2 v0 = mp[midx<OVER_HI>(u,     f)];
        float2 v1 = mp[midx<OVER_HI>(u + 1, f)];
        float2 v2 = mp[midx<OVER_HI>(u + 2, f)];
        float2 v3 = mp[midx<OVER_HI>(u + 3, f)];
        float2 v4 = mp[midx<OVER_HI>(u + 4, f)];
        float2 v5 = mp[midx<OVER_HI>(u + 5, f)];
        float2 v6 = mp[midx<OVER_HI>(u + 6, f)];
        float2 v7 = mp[midx<OVER_HI>(u + 7, f)];
        dif8(v0, v1, v2, v3, v4, v5, v6, v7);
        mp[midx<OVER_HI>(u,     f)] = v0;
        mp[midx<OVER_HI>(u + 1, f)] = v1;
        mp[midx<OVER_HI>(u + 2, f)] = v2;
        mp[midx<OVER_HI>(u + 3, f)] = v3;
        mp[midx<OVER_HI>(u + 4, f)] = v4;
        mp[midx<OVER_HI>(u + 5, f)] = v5;
        mp[midx<OVER_HI>(u + 6, f)] = v6;
        mp[midx<OVER_HI>(u + 7, f)] = v7;
    }
}
template<bool OVER_HI>
__device__ __forceinline__ void sweep_pair3_dit(float2* mp, const float2* tws, int tid) {
    #pragma unroll
    for (int it = 0; it < 4; ++it) {
        int qq = tid + (it << 10);
        int f = qq & 127, b = qq >> 7;
        int j = b & 7, g = b >> 3, u = (g << 5) + j;
        float2 v0 = mp[midx<OVER_HI>(u,      f)];
        float2 v1 = mp[midx<OVER_HI>(u + 8,  f)];
        float2 v2 = mp[midx<OVER_HI>(u + 16, f)];
        float2 v3 = mp[midx<OVER_HI>(u + 24, f)];
        dit_pair(v0, v1, v2, v3, tws[j << 3], tws[j << 2], tws[(j + 8) << 2]);
        mp[midx<OVER_HI>(u,      f)] = v0;
        mp[midx<OVER_HI>(u + 8,  f)] = v1;
        mp[midx<OVER_HI>(u + 16, f)] = v2;
        mp[midx<OVER_HI>(u + 24, f)] = v3;
    }
}
template<bool OVER_HI>
__device__ __forceinline__ void sweep_pair5_dit(float2* mp, const float2* tws, int tid) {
    #pragma unroll
    for (int it = 0; it < 4; ++it) {
        int qq = tid + (it << 10);
        int f = qq & 127, j = qq >> 7;
        float2 v0 = mp[midx<OVER_HI>(j,      f)];
        float2 v1 = mp[midx<OVER_HI>(j + 32, f)];
        float2 v2 = mp[midx<OVER_HI>(j + 64, f)];
        float2 v3 = mp[midx<OVER_HI>(j + 96, f)];
        dit_pair(v0, v1, v2, v3, tws[j << 1], tws[j], tws[j + 32]);
        mp[midx<OVER_HI>(j,      f)] = v0;
        mp[midx<OVER_HI>(j + 32, f)] = v1;
        mp[midx<OVER_HI>(j + 64, f)] = v2;
        mp[midx<OVER_HI>(j + 96, f)] = v3;
    }
}
// FWD rows pair6 with the mid twiddle twM[c*rev7(pos)] folded into the load.
__device__ __forceinline__ void sweep_pair6_dif_mid(float2* mp, const float2* tws,
                                                    const float2* twM, int tid) {
    #pragma unroll
    for (int it = 0; it < 4; ++it) {
        int qq = tid + (it << 10);
        int f = qq & 127, j = qq >> 7;           // f = hi = pos
        int rf = rev7(f);
        float2 v0 = cmul(mp[sidx(f, j)],      twM[j * rf]);
        float2 v1 = cmul(mp[sidx(f, j + 32)], twM[(j + 32) * rf]);
        float2 v2 = cmul(mp[sidx(f, j + 64)], twM[(j + 64) * rf]);
        float2 v3 = cmul(mp[sidx(f, j + 96)], twM[(j + 96) * rf]);
        dif_pair(v0, v1, v2, v3, tws[j], tws[j + 32], tws[j << 1]);
        mp[sidx(f, j)]      = v0;
        mp[sidx(f, j + 32)] = v1;
        mp[sidx(f, j + 64)] = v2;
        mp[sidx(f, j + 96)] = v3;
    }
}

// ---------------------------------------------------------------------------
// K0: per-bin scan of G for nonzero head/tail block sizes (exact-0 padding).
// ---------------------------------------------------------------------------
__global__ void k0_scan(const float* __restrict__ G, int NL, int* __restrict__ hnh) {
    const int j = blockIdx.x;
    __shared__ int s_first, s_last;
    if (threadIdx.x == 0) { s_first = NL; s_last = -1; }
    __syncthreads();
    const float* Gj = G + (size_t)j * NL;
    for (int m = threadIdx.x; m < NL; m += blockDim.x) {
        if (Gj[m] == 0.0f) {
            atomicMin(&s_first, m);
            atomicMax(&s_last, m);
        }
    }
    __syncthreads();
    if (threadIdx.x == 0) {
        int h  = s_first;
        int nh = (s_last >= 0) ? (NL - 1 - s_last) : 0;
        hnh[2 * j]     = h;
        hnh[2 * j + 1] = nh;
    }
}

// ---------------------------------------------------------------------------
// K1: 525-point DFT per (n2, r), split 525 = 25 x 21 (Cooley-Tukey in LDS).
// ---------------------------------------------------------------------------
__global__ __launch_bounds__(TPB) void k1_dft525(const float* __restrict__ x,
                                                 float2* __restrict__ A) {
    const int n2 = blockIdx.x;
    const int r  = blockIdx.y;
    __shared__ float  xs[N1];
    __shared__ float2 ys[N1];
    __shared__ float2 w25[25];
    __shared__ float2 w21[21];
    const float* xr = x + (size_t)r * LS + n2;
    for (int t = threadIdx.x; t < N1; t += TPB) {
        xs[t] = xr[(size_t)t * N2];
    }
    if (threadIdx.x < 25) {
        float a = -TWO_PI_F * (float)threadIdx.x / 25.0f;
        float s, c; sincosf(a, &s, &c);
        w25[threadIdx.x] = make_float2(c, s);
    } else if (threadIdx.x >= 32 && threadIdx.x < 53) {
        int k = threadIdx.x - 32;
        float a = -TWO_PI_F * (float)k / 21.0f;
        float s, c; sincosf(a, &s, &c);
        w21[k] = make_float2(c, s);
    }
    __syncthreads();
    for (int i = threadIdx.x; i < N1; i += TPB) {
        int alpha = i % 25, b = i / 25;
        float re = 0.f, im = 0.f;
        int iw = 0, it = b;
        #pragma unroll
        for (int a = 0; a < 25; ++a) {
            float  v = xs[it];
            float2 w = w25[iw];
            re = fmaf(v, w.x, re);
            im = fmaf(v, w.y, im);
            it += 21;
            iw += alpha; if (iw >= 25) iw -= 25;
        }
        float ang = -TWO_PI_F * (float)(b * alpha) / (float)N1;
        float s, c; sincosf(ang, &s, &c);
        ys[i] = make_float2(re * c - im * s, re * s + im * c);
    }
    __syncthreads();
    for (int k = threadIdx.x; k < N1; k += TPB) {
        int alpha = k % 25, beta = k / 25;
        float re = 0.f, im = 0.f;
        int iw = 0, iy = alpha;
        #pragma unroll
        for (int b = 0; b < 21; ++b) {
            float2 v = ys[iy];
            float2 w = w21[iw];
            re = fmaf(v.x, w.x, re); re = fmaf(-v.y, w.y, re);
            im = fmaf(v.x, w.y, im); im = fmaf( v.y, w.x, im);
            iy += 25;
            iw += beta; if (iw >= 21) iw -= 21;
        }
        float ang = -TWO_PI_F * (float)(k * n2) / (float)LS;
        float s, c; sincosf(ang, &s, &c);
        A[((size_t)r * N1 + k) * N2 + n2] = make_float2(re * c - im * s, re * s + im * c);
    }
}

// ---------------------------------------------------------------------------
// K2: 504-point DFT per (k1, r), split 504 = 21 x 24 (Cooley-Tukey in LDS).
// ---------------------------------------------------------------------------
__global__ __launch_bounds__(TPB) void k2_dft504(float2* __restrict__ A) {
    const int k1 = blockIdx.x;
    const int r  = blockIdx.y;
    __shared__ float2 as[N2];
    __shared__ float2 ys[N2];
    __shared__ float2 w21[21];
    __shared__ float2 w24[24];
    float2* row = A + ((size_t)r * N1 + k1) * N2;
    for (int t = threadIdx.x; t < N2; t += TPB) as[t] = row[t];
    if (threadIdx.x < 21) {
        float a = -TWO_PI_F * (float)threadIdx.x / 21.0f;
        float s, c; sincosf(a, &s, &c);
        w21[threadIdx.x] = make_float2(c, s);
    } else if (threadIdx.x >= 32 && threadIdx.x < 56) {
        int k = threadIdx.x - 32;
        float a = -TWO_PI_F * (float)k / 24.0f;
        float s, c; sincosf(a, &s, &c);
        w24[k] = make_float2(c, s);
    }
    __syncthreads();
    for (int i = threadIdx.x; i < N2; i += TPB) {
        int alpha = i % 21, b = i / 21;
        float re = 0.f, im = 0.f;
        int iw = 0, it = b;
        #pragma unroll
        for (int a = 0; a < 21; ++a) {
            float2 v = as[it];
            float2 w = w21[iw];
            re = fmaf(v.x, w.x, re); re = fmaf(-v.y, w.y, re);
            im = fmaf(v.x, w.y, im); im = fmaf( v.y, w.x, im);
            it += 24;
            iw += alpha; if (iw >= 21) iw -= 21;
        }
        float ang = -TWO_PI_F * (float)(b * alpha) / (float)N2;
        float s, c; sincosf(ang, &s, &c);
        ys[i] = make_float2(re * c - im * s, re * s + im * c);
    }
    __syncthreads();
    for (int k = threadIdx.x; k < N2; k += TPB) {
        int alpha = k % 21, beta = k / 21;
        float re = 0.f, im = 0.f;
        int iw = 0, iy = alpha;
        #pragma unroll
        for (int b = 0; b < 24; ++b) {
            float2 v = ys[iy];
            float2 w = w24[iw];
            re = fmaf(v.x, w.x, re); re = fmaf(-v.y, w.y, re);
            im = fmaf(v.x, w.y, im); im = fmaf( v.y, w.x, im);
            iy += 21;
            iw += beta; if (iw >= 24) iw -= 24;
        }
        row[k] = make_float2(re, im);
    }
}

// ---------------------------------------------------------------------------
// K_SETUP: chirp tables + W_128 table + 16K-entry W_M table.
// ---------------------------------------------------------------------------
__global__ void k_setup(float2* __restrict__ kc, float2* __restrict__ bchirp,
                        float2* __restrict__ twg, float2* __restrict__ twM, int NL) {
    int t = blockIdx.x * blockDim.x + threadIdx.x;
    long long twoNL = 2LL * NL;
    if (t < M_FFT) {
        long long d = 0; bool act = false;
        if (t < NL)              { d = t;        act = true; }
        else if (t > M_FFT - NL) { d = t - M_FFT; act = true; }
        float2 v = make_float2(0.f, 0.f);
        if (act) {
            long long ph = (d * d) % twoNL;
            float th = -PI_F * (float)ph / (float)NL;
            float s, c; sincosf(th, &s, &c);
            v = make_float2(c, s);
        }
        kc[t] = v;
    } else {
        int n = t - M_FFT;
        if (n < NL) {
            long long ph = ((long long)n * n) % twoNL;
            float th = PI_F * (float)ph / (float)NL;
            float s, c; sincosf(th, &s, &c);
            bchirp[n] = make_float2(c, s);
        } else if (n < NL + 128) {
            int q = n - NL;
            float th = -TWO_PI_F * (float)q / 128.0f;
            float s, c; sincosf(th, &s, &c);
            twg[q] = make_float2(c, s);
        } else if (n < NL + 128 + M_FFT) {
            int q = n - NL - 128;
            float th = -TWO_PI_F * (float)q / (float)M_FFT;
            float s, c; sincosf(th, &s, &c);
            twM[q] = make_float2(c, s);
        }
    }
}

// ---------------------------------------------------------------------------
// K_KF: one block. KF[i] = fwd-pipeline(kc) in scrambled flat layout.
// ---------------------------------------------------------------------------
__global__ __launch_bounds__(TPF) void k_kf(const float2* __restrict__ kc,
        const float2* __restrict__ twg, const float2* __restrict__ twM,
        float2* __restrict__ KF) {
    extern __shared__ float2 mp[];
    __shared__ float2 tws[64];
    const int tid = threadIdx.x;
    if (tid < 64) tws[tid] = twg[tid];
    for (int i = tid; i < M_FFT; i += TPF)
        mp[sidx(i >> 7, i & 127)] = kc[i];
    __syncthreads();
    sweep_pair6_dif<true>(mp, tws, tid);  __syncthreads();
    sweep_pair4_dif<true>(mp, tws, tid);  __syncthreads();
    sweep_oct_dif<true>(mp, tid);         __syncthreads();
    sweep_pair6_dif_mid(mp, tws, twM, tid); __syncthreads();
    sweep_pair4_dif<false>(mp, tws, tid); __syncthreads();
    sweep_oct_dif<false>(mp, tid);        __syncthreads();
    for (int i = tid; i < M_FFT; i += TPF)
        KF[i] = mp[sidx(i >> 7, i & 127)];
}

// ---------------------------------------------------------------------------
// K_FUSED: one transform per block. 12 sweeps, max 8 live float2/phase:
//  S1  fwd cols pair(6,5) + gather fold        S7  inv rows oct(0,1,2) + xKF
//  S2  fwd cols pair(4,3)                      S8  inv rows pair(3,4)
//  S3  fwd cols oct(2,1,0)                     S9  inv rows pair(5,6)
//  S4  fwd rows pair(6,5) + mid twiddle        S10 inv cols oct(0,1,2) + inv mid
//  S5  fwd rows pair(4,3)                      S11 inv cols pair(3,4)
//  S6  fwd rows oct(2,1,0)                     S12 inv cols pair(5,6) + out fold
// ---------------------------------------------------------------------------
#define GATH(var, I) do {                                                     \
    (var) = make_float2(0.f, 0.f);                                            \
    const int i_ = (I);                                                       \
    if (i_ < h || (i_ >= tail0 && i_ < NL)) {                                 \
        int k_ = ij[i_];                                                      \
        float2 f_ = Ar[(size_t)(k_ % N1) * N2 + (k_ / N1)];                   \
        float  g_ = Gj[i_];                                                   \
        (var) = cmul(make_float2(f_.x * g_, f_.y * g_), bchirp[i_]);          \
    }                                                                         \
} while (0)

__global__ __launch_bounds__(TPF) void k_fused(const float* __restrict__ Gm,
        const int* __restrict__ idxp, const float2* __restrict__ A,
        const int* __restrict__ hnh, const float2* __restrict__ bchirp,
        const float2* __restrict__ KF, const float2* __restrict__ twg,
        const float2* __restrict__ twM,
        float2* __restrict__ out, int NB, int NL) {
    extern __shared__ float2 mp[];
    __shared__ float2 tws[64];
    const int tid = threadIdx.x;
    if (tid < 64) tws[tid] = twg[tid];
    const int vg = blockIdx.x;
    const int rr_ = vg / NB, jb = vg % NB;
    const int h = hnh[2 * jb], nh = hnh[2 * jb + 1];
    const int tail0 = NL - nh;
    const float* Gj = Gm + (size_t)jb * NL;
    const int*   ij = idxp + (size_t)jb * NL;
    const float2* Ar = A + (size_t)rr_ * LS;
    __syncthreads();                                  // tws ready

    // S1: fwd cols pair(6,5) with gather fold (flat i = hi*128 + lo)
    #pragma unroll
    for (int it = 0; it < 4; ++it) {
        int qq = tid + (it << 10);
        int f = qq & 127, j = qq >> 7;
        float2 v0, v1, v2, v3;
        GATH(v0, (j     ) * 128 + f);
        GATH(v1, (j + 32) * 128 + f);
        GATH(v2, (j + 64) * 128 + f);
        GATH(v3, (j + 96) * 128 + f);
        dif_pair(v0, v1, v2, v3, tws[j], tws[j + 32], tws[j << 1]);
        mp[sidx(j,      f)] = v0;
        mp[sidx(j + 32, f)] = v1;
        mp[sidx(j + 64, f)] = v2;
        mp[sidx(j + 96, f)] = v3;
    }
    __syncthreads();
    sweep_pair4_dif<true>(mp, tws, tid);  __syncthreads();   // S2
    sweep_oct_dif<true>(mp, tid);         __syncthreads();   // S3
    sweep_pair6_dif_mid(mp, tws, twM, tid); __syncthreads(); // S4
    sweep_pair4_dif<false>(mp, tws, tid); __syncthreads();   // S5
    sweep_oct_dif<false>(mp, tid);        __syncthreads();   // S6

    // S7: inv rows oct(0,1,2) with xKF fold (KF flat i = hi*128 + lo)
    #pragma unroll
    for (int it = 0; it < 2; ++it) {
        int qq = tid + (it << 10);
        int f = qq & 127, u = (qq >> 7) << 3;
        const float2* KFr = KF + (size_t)f * 128 + u;
        float2 v0 = cmul(mp[sidx(f, u)],     KFr[0]);
        float2 v1 = cmul(mp[sidx(f, u + 1)], KFr[1]);
        float2 v2 = cmul(mp[sidx(f, u + 2)], KFr[2]);
        float2 v3 = cmul(mp[sidx(f, u + 3)], KFr[3]);
        float2 v4 = cmul(mp[sidx(f, u + 4)], KFr[4]);
        float2 v5 = cmul(mp[sidx(f, u + 5)], KFr[5]);
        float2 v6 = cmul(mp[sidx(f, u + 6)], KFr[6]);
        float2 v7 = cmul(mp[sidx(f, u + 7)], KFr[7]);
        dit8(v0, v1, v2, v3, v4, v5, v6, v7);
        mp[sidx(f, u)]     = v0;
        mp[sidx(f, u + 1)] = v1;
        mp[sidx(f, u + 2)] = v2;
        mp[sidx(f, u + 3)] = v3;
        mp[sidx(f, u + 4)] = v4;
        mp[sidx(f, u + 5)] = v5;
        mp[sidx(f, u + 6)] = v6;
        mp[sidx(f, u + 7)] = v7;
    }
    __syncthreads();
    sweep_pair3_dit<false>(mp, tws, tid); __syncthreads();   // S8
    sweep_pair5_dit<false>(mp, tws, tid); __syncthreads();   // S9

    // S10: inv cols oct(0,1,2) with inverse mid twiddle conj(twM[rev7(R)*pos])
    #pragma unroll
    for (int it = 0; it < 2; ++it) {
        int qq = tid + (it << 10);
        int f = qq & 127, u = (qq >> 7) << 3;
        float2 v0 = cmulc(mp[sidx(u,     f)], twM[rev7(u)     * f]);
        float2 v1 = cmulc(mp[sidx(u + 1, f)], twM[rev7(u + 1) * f]);
        float2 v2 = cmulc(mp[sidx(u + 2, f)], twM[rev7(u + 2) * f]);
        float2 v3 = cmulc(mp[sidx(u + 3, f)], twM[rev7(u + 3) * f]);
        float2 v4 = cmulc(mp[sidx(u + 4, f)], twM[rev7(u + 4) * f]);
        float2 v5 = cmulc(mp[sidx(u + 5, f)], twM[rev7(u + 5) * f]);
        float2 v6 = cmulc(mp[sidx(u + 6, f)], twM[rev7(u + 6) * f]);
        float2 v7 = cmulc(mp[sidx(u + 7, f)], twM[rev7(u + 7) * f]);
        dit8(v0, v1, v2, v3, v4, v5, v6, v7);
        mp[sidx(u,     f)] = v0;
        mp[sidx(u + 1, f)] = v1;
        mp[sidx(u + 2, f)] = v2;
        mp[sidx(u + 3, f)] = v3;
        mp[sidx(u + 4, f)] = v4;
        mp[sidx(u + 5, f)] = v5;
        mp[sidx(u + 6, f)] = v6;
        mp[sidx(u + 7, f)] = v7;
    }
    __syncthreads();
    sweep_pair3_dit<true>(mp, tws, tid); __syncthreads();    // S11

    // S12: inv cols pair(5,6) + output fold (y natural at flat n = hi*128+lo)
    const float sc = 100.0f / ((float)NL * (float)M_FFT);
    float2* outv = out + (size_t)vg * NL;
    #pragma unroll
    for (int it = 0; it < 4; ++it) {
        int qq = tid + (it << 10);
        int f = qq & 127, j = qq >> 7;
        float2 v0 = mp[sidx(j,      f)];
        float2 v1 = mp[sidx(j + 32, f)];
        float2 v2 = mp[sidx(j + 64, f)];
        float2 v3 = mp[sidx(j + 96, f)];
        dit_pair(v0, v1, v2, v3, tws[j << 1], tws[j], tws[j + 32]);
        int n0 = (j)      * 128 + f;
        int n1 = (j + 32) * 128 + f;
        int n2_ = (j + 64) * 128 + f;
        int n3 = (j + 96) * 128 + f;
        if (n0 < NL) { float2 y = cmul(v0, bchirp[n0]); outv[n0] = make_float2(y.x * sc, y.y * sc); }
        if (n1 < NL) { float2 y = cmul(v1, bchirp[n1]); outv[n1] = make_float2(y.x * sc, y.y * sc); }
        if (n2_ < NL) { float2 y = cmul(v2, bchirp[n2_]); outv[n2_] = make_float2(y.x * sc, y.y * sc); }
        if (n3 < NL) { float2 y = cmul(v3, bchirp[n3]); outv[n3] = make_float2(y.x * sc, y.y * sc); }
    }
}

// ---------------------------------------------------------------------------
// Legacy direct zoom-IDFT — fallback if NL too large or ws too small.
// ---------------------------------------------------------------------------
__global__ __launch_bounds__(TPB) void k3_idft(const float* __restrict__ G,
                                               const int*  __restrict__ idxp,
                                               const float2* __restrict__ FT,
                                               const int*  __restrict__ hnh,
                                               float2* __restrict__ out,
                                               int NB, int NL) {
    extern __shared__ float2 cls[];
    const int j = blockIdx.x;
    const int r = blockIdx.y;
    const int h  = hnh[2 * j];
    const int nh = hnh[2 * j + 1];
    const int Lg = h + nh;
    const float* Gj = G    + (size_t)j * NL;
    const int*   ij = idxp + (size_t)j * NL;

    for (int t = threadIdx.x; t < Lg; t += TPB) {
        int m = (t < h) ? t : (NL - nh + (t - h));
        int k = ij[m];
        float2 f = FT[((size_t)r * N1 + (k % N1)) * N2 + (k / N1)];
        float  g = Gj[m];
        cls[t] = make_float2(f.x * g, f.y * g);
    }
    __syncthreads();

    const float scale = 100.0f / (float)NL;
    const float w0 = TWO_PI_F / (float)NL;
    float2* outr = out + ((size_t)r * NB + j) * NL;

    for (int n_base = 0; n_base < NL; n_base += 4 * TPB) {
        int   n[4];
        float are[4], aim[4], twr[4], twi[4], str[4], sti[4];
        #pragma unroll
        for (int u = 0; u < 4; ++u) {
            n[u] = n_base + u * TPB + (int)threadIdx.x;
            are[u] = 0.f; aim[u] = 0.f;
            float s, c; sincosf(w0 * (float)(n[u] % NL), &s, &c);
            str[u] = c; sti[u] = s;
            twr[u] = 1.f; twi[u] = 0.f;
        }
        for (int t = 0; t < h; ++t) {
            if ((t & 255) == 0) {
                #pragma unroll
                for (int u = 0; u < 4; ++u) {
                    int mm = (int)(((long long)t * (long long)n[u]) % NL);
                    float s, c; sincosf(w0 * (float)mm, &s, &c);
                    twr[u] = c; twi[u] = s;
                }
            }
            float2 cv = cls[t];
            #pragma unroll
            for (int u = 0; u < 4; ++u) {
                are[u] = fmaf(cv.x, twr[u], are[u]);
                are[u] = fmaf(-cv.y, twi[u], are[u]);
                aim[u] = fmaf(cv.x, twi[u], aim[u]);
                aim[u] = fmaf(cv.y, twr[u], aim[u]);
                float nr = twr[u] * str[u] - twi[u] * sti[u];
                float ni = twr[u] * sti[u] + twi[u] * str[u];
                twr[u] = nr; twi[u] = ni;
            }
        }
        const int m0 = NL - nh;
        for (int t = 0; t < nh; ++t) {
            if ((t & 255) == 0) {
                #pragma unroll
                for (int u = 0; u < 4; ++u) {
                    int mm = (int)(((long long)(m0 + t) * (long long)n[u]) % NL);
                    float s, c; sincosf(w0 * (float)mm, &s, &c);
                    twr[u] = c; twi[u] = s;
                }
            }
            float2 cv = cls[h + t];
            #pragma unroll
            for (int u = 0; u < 4; ++u) {
                are[u] = fmaf(cv.x, twr[u], are[u]);
                are[u] = fmaf(-cv.y, twi[u], are[u]);
                aim[u] = fmaf(cv.x, twi[u], aim[u]);
                aim[u] = fmaf(cv.y, twr[u], aim[u]);
                float nr = twr[u] * str[u] - twi[u] * sti[u];
                float ni = twr[u] * sti[u] + twi[u] * str[u];
                twr[u] = nr; twi[u] = ni;
            }
        }
        #pragma unroll
        for (int u = 0; u < 4; ++u) {
            if (n[u] < NL) outr[n[u]] = make_float2(are[u] * scale, aim[u] * scale);
        }
    }
}

// ---------------------------------------------------------------------------
static inline size_t align256(size_t x) { return (x + 255) & ~(size_t)255; }

extern "C" void kernel_launch(void* const* d_in, const int* in_sizes, int n_in,
                              void* d_out, int out_size, void* d_ws, size_t ws_size,
                              hipStream_t stream) {
    const float* x   = (const float*)d_in[0];
    const float* Gm  = (const float*)d_in[1];
    const int*   idx = (const int*)d_in[2];
    float2*      out = (float2*)d_out;

    const int p  = in_sizes[1];
    const int NB = (p % 114 == 0) ? 114 : 115;
    const int NL = p / NB;
    const int B  = NB * ROWS;

    // ws layout: hnh | bchirp | twg(128) | twM(16384) | kc | KF | A
    size_t hnh_off    = 0;
    size_t bchirp_off = align256(hnh_off + 2048);
    size_t twg_off    = align256(bchirp_off + (size_t)NL * 8);
    size_t twM_off    = align256(twg_off + 128 * 8);
    size_t kc_off     = align256(twM_off + (size_t)M_FFT * 8);
    size_t kf_off     = align256(kc_off + (size_t)M_FFT * 8);
    size_t A_off      = align256(kf_off + (size_t)M_FFT * 8);
    size_t need       = A_off + (size_t)ROWS * LS * 8;

    int*    hnh    = (int*)((char*)d_ws + hnh_off);
    float2* bchirp = (float2*)((char*)d_ws + bchirp_off);
    float2* twg    = (float2*)((char*)d_ws + twg_off);
    float2* twM    = (float2*)((char*)d_ws + twM_off);
    float2* kc     = (float2*)((char*)d_ws + kc_off);
    float2* KF     = (float2*)((char*)d_ws + kf_off);
    float2* A      = (float2*)((char*)d_ws + A_off);

    k0_scan<<<dim3(NB), TPB, 0, stream>>>(Gm, NL, hnh);
    k1_dft525<<<dim3(N2, ROWS), TPB, 0, stream>>>(x, A);
    k2_dft504<<<dim3(N1, ROWS), TPB, 0, stream>>>(A);

    const bool fused_ok = (2 * NL - 1 <= M_FFT) && (need <= ws_size);
    if (fused_ok) {
        (void)hipFuncSetAttribute((const void*)k_fused,
                                  hipFuncAttributeMaxDynamicSharedMemorySize,
                                  M_FFT * (int)sizeof(float2));
        (void)hipFuncSetAttribute((const void*)k_kf,
                                  hipFuncAttributeMaxDynamicSharedMemorySize,
                                  M_FFT * (int)sizeof(float2));
        int setup_blocks = (2 * M_FFT + NL + 128 + TPB - 1) / TPB;
        k_setup<<<dim3(setup_blocks), TPB, 0, stream>>>(kc, bchirp, twg, twM, NL);
        k_kf<<<dim3(1), TPF, (size_t)M_FFT * sizeof(float2), stream>>>(kc, twg, twM, KF);
        k_fused<<<dim3(B), TPF, (size_t)M_FFT * sizeof(float2), stream>>>(
            Gm, idx, A, hnh, bchirp, KF, twg, twM, out, NB, NL);
    } else {
        k3_idft<<<dim3(NB, ROWS), TPB, (size_t)NL * sizeof(float2), stream>>>(
            Gm, idx, A, hnh, out, NB, NL);
    }
}